// Round 6
// baseline (228.332 us; speedup 1.0000x reference)
//
#include <hip/hip_runtime.h>
#include <hip/hip_bf16.h>

// B=4, L=2048, DIM=512, H=8, D=64, fp32 in/out.
// pack fp32->fp16 (log2e folded into wq) -> fused QKV MFMA GEMM (BK=64, V^T
// via in-LDS transpose epilogue) -> 32x32x16-MFMA flash attn (64q/wave,
// 4-way key-split waves, 128-key rounds, K STRAIGHT FROM GLOBAL into MFMA
// A-frags [wave-private rows -> no K LDS, no K barriers], V double-buffered
// gl2lds with counted vmcnt + 2 raw barriers/round [T3/T4, 33.8KB LDS ->
// 3 blocks/CU], setprio [T5], permlane32_swap P-transform, in-place exp2)
// -> out-proj MFMA GEMM.
// NOTE: global_load_lds imm offset applies to the GLOBAL address only; the
// LDS dest is always M0 + lane*16 -> multi-call staging must bump BOTH ptrs.
// NOTE (R3-R5 lesson): ANY K-in-LDS single-buffer variant needs mid-round
// staging + a 3rd barrier/fence cluster; values live across that cluster
// made the allocator spill ~2 dwords/thread/round -> 30 MB scratch traffic,
// 2x slowdown, at VGPR counts that "should" fit. The 2-barrier top-staged
// shape (R0/R1) never spills. K rows are consumed wave-privately, so K
// doesn't need LDS at all: 4 global_load_dwordx4 per wave per round; the
// s=0..3 frags of a lane pair cover a full 128B K row -> L1-line efficient;
// K is L2-resident across the 32 qb blocks per head.
// NOTE vmcnt accounting per round r (parity P):
//   top: issue kf(r) x4 (oldest) -> issue V(r+1) x4 into Vb(P^1)
//        -> vmcnt(4) retires {V(r), kf(r)}, leaves V(r+1) in flight
//        -> s_barrier (publishes V(r) staging cross-wave)
//   QK (kf regs) -> softmax -> PV reads Vb(P) -> s_barrier (protects Vb(P)
//   from round r+1's V(r+2) issue; R2 race lesson). vmcnt(0) last round.

#define Bsz 4
#define Lsz 2048
#define DIMsz 512
#define Hsz 8
#define Dsz 64

typedef _Float16 f16;
typedef __attribute__((ext_vector_type(8))) _Float16 f16x8;
typedef __attribute__((ext_vector_type(4))) _Float16 f16x4;
typedef __attribute__((ext_vector_type(2))) __fp16 fp16x2;  // builtin ret type
typedef __attribute__((ext_vector_type(4))) float f32x4;
typedef __attribute__((ext_vector_type(16))) float f32x16;
typedef unsigned int u32;
typedef __attribute__((ext_vector_type(2))) unsigned int u32x2;

#if __has_builtin(__builtin_amdgcn_exp2f)
#define EXP2(x) __builtin_amdgcn_exp2f(x)
#else
#define EXP2(x) __expf(0.6931471805599453f * (x))
#endif

__device__ __forceinline__ u32 pack2(float a, float b) {
#if __has_builtin(__builtin_amdgcn_cvt_pkrtz)
    fp16x2 h = __builtin_amdgcn_cvt_pkrtz(a, b);
    return __builtin_bit_cast(u32, h);
#else
    fp16x2 h; h.x = (__fp16)a; h.y = (__fp16)b;
    return __builtin_bit_cast(u32, h);
#endif
}

// Cross-half exchange for the 32x32 C->B P-transform.
#if __has_builtin(__builtin_amdgcn_permlane32_swap)
__device__ __forceinline__ void plswap(u32& a, u32& b) {
    u32x2 r = __builtin_amdgcn_permlane32_swap(a, b, false, false);
    a = r.x; b = r.y;
}
#else
__device__ __forceinline__ void plswap(u32& a, u32& b) {
    u32 sa = (u32)__shfl_xor((int)a, 32);
    u32 sb = (u32)__shfl_xor((int)b, 32);
    bool hi = (threadIdx.x & 32) != 0;
    u32 na = hi ? sb : a;
    u32 nb = hi ? b : sa;
    a = na; b = nb;
}
#endif

__device__ __forceinline__ void gl2lds16(const void* g, void* l) {
    __builtin_amdgcn_global_load_lds(
        (const __attribute__((address_space(1))) u32*)g,
        (__attribute__((address_space(3))) u32*)l, 16, 0, 0);
}

// ---------------- pack: fp32 -> fp16 ----------------------------------------
__global__ __launch_bounds__(256) void pack_f16(
    const float* __restrict__ x, const float* __restrict__ wq,
    const float* __restrict__ wk, const float* __restrict__ wv,
    const float* __restrict__ wo,
    f16* __restrict__ xh, f16* __restrict__ w3h, f16* __restrict__ woh)
{
    int bx = blockIdx.x, seg, blk;
    if (bx < 4096) { seg = 0; blk = bx; }
    else { seg = 1 + ((bx - 4096) >> 8); blk = (bx - 4096) & 255; }
    const float* s; f16* d; float sc = 1.0f;
    switch (seg) {
        case 0: s = x;  d = xh;            break;
        case 1: s = wq; d = w3h;           sc = 0.18033688011112042f; break;
        case 2: s = wk; d = w3h + 262144;  break;
        case 3: s = wv; d = w3h + 524288;  break;
        default: s = wo; d = woh;          break;
    }
    int i = (blk * 256 + threadIdx.x) * 4;
    float4 v = *(const float4*)(s + i);
    f16x4 o;
    o.x = (f16)(v.x * sc); o.y = (f16)(v.y * sc);
    o.z = (f16)(v.z * sc); o.w = (f16)(v.w * sc);
    *(f16x4*)(d + i) = o;
}

// ---------------- fused QKV MFMA GEMM (BK=64) --------------------------------
__global__ __launch_bounds__(256) void gemm_qkv_f16(
    const f16* __restrict__ A, const f16* __restrict__ B,
    f16* __restrict__ qh, f16* __restrict__ kh, f16* __restrict__ vth)
{
    __shared__ __align__(16) char smem[32768];   // A 16K | B 16K ; Tv reuse
    f16* Ash = (f16*)smem;
    f16* Bsh = (f16*)(smem + 16384);

    const int tid = threadIdx.x;
    const int w = tid >> 6, lane = tid & 63;
    const int quad = lane >> 4, low = lane & 15;
    const int wm = w >> 1, wn = w & 1;
    const int m0 = blockIdx.y * 128, n0 = blockIdx.x * 128;

    f32x4 acc[4][4];
    #pragma unroll
    for (int i = 0; i < 4; i++)
        #pragma unroll
        for (int j = 0; j < 4; j++) acc[i][j] = (f32x4){0.f, 0.f, 0.f, 0.f};

    #pragma unroll 1
    for (int k0 = 0; k0 < DIMsz; k0 += 64) {
        __syncthreads();
        #pragma unroll
        for (int j = 0; j < 4; j++) {
            int t = j * 256 + tid;
            int r = t >> 3, g = t & 7;                 // 128 rows x 8 chunks
            int gc = (g ^ (r & 7)) * 8;
            char* lb = (char*)Ash + (j * 256 + w * 64) * 16;
            gl2lds16(A + (size_t)(m0 + r) * DIMsz + k0 + gc, lb);
            char* lb2 = (char*)Bsh + (j * 256 + w * 64) * 16;
            gl2lds16(B + (size_t)(n0 + r) * DIMsz + k0 + gc, lb2);
        }
        __syncthreads();

        #pragma unroll
        for (int ks2 = 0; ks2 < 2; ks2++) {
            f16x8 af[4], bf[4];
            #pragma unroll
            for (int mt = 0; mt < 4; mt++) {
                int ar = wm * 64 + mt * 16 + low;
                int c = ks2 * 4 + quad;
                af[mt] = *(const f16x8*)&Ash[ar * 64 + ((c ^ (ar & 7)) << 3)];
            }
            #pragma unroll
            for (int nt = 0; nt < 4; nt++) {
                int br = wn * 64 + nt * 16 + low;
                int c = ks2 * 4 + quad;
                bf[nt] = *(const f16x8*)&Bsh[br * 64 + ((c ^ (br & 7)) << 3)];
            }
            #pragma unroll
            for (int mt = 0; mt < 4; mt++)
                #pragma unroll
                for (int nt = 0; nt < 4; nt++)
                    acc[mt][nt] = __builtin_amdgcn_mfma_f32_16x16x32_f16(
                        af[mt], bf[nt], acc[mt][nt], 0, 0, 0);
        }
    }

    const int proj = n0 >> 9;                 // uniform per block
    if (proj < 2) {
        f16* dst = (proj == 0) ? qh : kh;
        #pragma unroll
        for (int nt = 0; nt < 4; nt++) {
            int n = n0 + wn * 64 + nt * 16 + low;
            int c = n & 511, h = c >> 6, d = c & 63;
            #pragma unroll
            for (int mt = 0; mt < 4; mt++)
                #pragma unroll
                for (int r = 0; r < 4; r++) {
                    int m = m0 + wm * 64 + mt * 16 + quad * 4 + r;
                    int b_ = m >> 11, l = m & (Lsz - 1);
                    size_t bh = (size_t)(b_ * Hsz + h);
                    dst[(bh * Lsz + l) * Dsz + d] = (f16)acc[mt][nt][r];
                }
        }
    } else {
        // v: transpose per head through LDS, then coalesced stores
        const int hb = (n0 & 511) >> 6;
        f16* Tv = (f16*)smem;                 // [64 d][136]
        const int b_ = m0 >> 11, l0 = m0 & (Lsz - 1);
        #pragma unroll 1
        for (int hs = 0; hs < 2; hs++) {
            __syncthreads();
            if (wn == hs) {
                #pragma unroll
                for (int nt = 0; nt < 4; nt++) {
                    int d = nt * 16 + low;
                    #pragma unroll
                    for (int mt = 0; mt < 4; mt++)
                        #pragma unroll
                        for (int r = 0; r < 4; r++) {
                            int l = wm * 64 + mt * 16 + quad * 4 + r;
                            Tv[d * 136 + l] = (f16)acc[mt][nt][r];
                        }
                }
            }
            __syncthreads();
            int d = tid >> 2, seg = tid & 3;
            size_t bh = (size_t)(b_ * Hsz + hb + hs);
            f16* dstp = vth + (bh * 64 + d) * (size_t)Lsz + l0 + seg * 32;
            const f16* srcp = Tv + d * 136 + seg * 32;
            #pragma unroll
            for (int j = 0; j < 4; j++)
                *(f16x8*)(dstp + j * 8) = *(const f16x8*)(srcp + j * 8);
        }
    }
}

// ---------------- MFMA flash attention (64q/wave, 4-way key split) -----------
// grid (B*H=32 fastest -> XCD locality, L/64=32), block 256 = 4 waves = 64 q.
// Each round covers 128 keys; wave w owns keys w*32..+31 and computes them
// against ALL 64 q (2 B-operand q-tiles) -> K/V frag reads amortize 2x.
// K: per-wave global loads into A-frags (no LDS). V: LDS double buffer.
// LDS 33KB: Vb0 [0,16K), Vb1 [16K,32K), Ls [32K,33K).
// 4-way split-K O/lsum merge via reused staging LDS at the end.
__global__ __launch_bounds__(256, 3) void attn_mfma(
    const f16* __restrict__ q, const f16* __restrict__ k,
    const f16* __restrict__ vt, f16* __restrict__ ctx)
{
    __shared__ __align__(16) char smem[33792];

    const int tid = threadIdx.x;
    const int w = tid >> 6, lane = tid & 63;
    const int col = lane & 31;
    const int h = lane >> 5;
    const int bh = blockIdx.x;        // fastest -> 4 heads per XCD
    const int qb = blockIdx.y;
    const int q0 = qb * 64;
    const size_t kvb = (size_t)bh * Lsz;

    f16* Vs = (f16*)smem;             // buf0 [64 d][128 key], 16-chunk XOR swz

    // Q B-frags for 2 q-tiles: B[k=d][n=q], lane n=col, k = s*16 + h*8 + j
    f16x8 qf[2][4];
    #pragma unroll
    for (int qt = 0; qt < 2; qt++)
        #pragma unroll
        for (int s = 0; s < 4; s++)
            qf[qt][s] = *(const f16x8*)(q + (kvb + q0 + qt * 32 + col) * Dsz
                                          + s * 16 + h * 8);
    // Force q loads live so the compiler doesn't re-wait for them in-loop.
    #pragma unroll
    for (int qt = 0; qt < 2; qt++)
        #pragma unroll
        for (int s = 0; s < 4; s++)
            asm volatile("" :: "v"(qf[qt][s]));

    // K A-frag global base: lane reads row w*32+col, d = s*16 + h*8 .. +7.
    // The s=0..3 frags of lanes (col,h=0/1) cover the full 128B row.
    const f16* kgb = k + (kvb + w * 32 + col) * Dsz + h * 8;

    // V staging source base pointer (lane-specific, bumped per round)
    const f16* vp;
    {
        int rv_ = tid >> 4, gv = tid & 15;        // vp covers d rows 0..15
        vp = vt + ((size_t)bh * Dsz + rv_) * Lsz + ((gv ^ (rv_ & 15)) << 3);
    }
    char* vl = (char*)smem + w * 1024;            // wave-uniform LDS dest

    // V frag base pointers (2; dt adds +8192B, parity adds +16384B)
    const f16* vfb[2];
    #pragma unroll
    for (int ks = 0; ks < 2; ks++) {
        int cv = w * 4 + ks * 2 + h;
        vfb[ks] = Vs + col * 128 + ((cv ^ (col & 15)) << 3);
    }

    f32x16 acc[2][2];                 // O^T partial [qt][dt], cols = q
    #pragma unroll
    for (int qt = 0; qt < 2; qt++)
        #pragma unroll
        for (int dt = 0; dt < 2; dt++)
            #pragma unroll
            for (int i = 0; i < 16; i++) acc[qt][dt][i] = 0.f;
    float lsum[2] = {0.f, 0.f};

    const int drd_s0 = (qb >> 1) * 128;           // round containing the diag
    const int dqt = w - (qb & 1) * 2;             // qt this wave diag-masks

    // prologue: V(0) -> Vb0
    gl2lds16(vp,            vl);
    gl2lds16(vp + 16 * Lsz, vl + 4096);
    gl2lds16(vp + 32 * Lsz, vl + 8192);
    gl2lds16(vp + 48 * Lsz, vl + 12288);
    vp += 128;

// Round r (parity P, PRE = rounds remain). kf(r) issued FIRST (older than
// V(r+1)) so vmcnt(4) retires {V(r), kf(r)} and leaves V(r+1) in flight.
#define ATTN_ROUND(S0, P, PRE) do {                                           \
    f16x8 kf0 = *(const f16x8*)(kgb);                                         \
    f16x8 kf1 = *(const f16x8*)(kgb + 16);                                    \
    f16x8 kf2 = *(const f16x8*)(kgb + 32);                                    \
    f16x8 kf3 = *(const f16x8*)(kgb + 48);                                    \
    kgb += 128 * Dsz;                                                         \
    __builtin_amdgcn_sched_barrier(0);                                        \
    if (PRE) {                                                                \
        const int nv_ = ((P) ^ 1) * 16384;                                    \
        gl2lds16(vp,            vl + nv_);                                    \
        gl2lds16(vp + 16 * Lsz, vl + nv_ + 4096);                             \
        gl2lds16(vp + 32 * Lsz, vl + nv_ + 8192);                             \
        gl2lds16(vp + 48 * Lsz, vl + nv_ + 12288);                            \
        vp += 128;                                                            \
        asm volatile("s_waitcnt vmcnt(4)" ::: "memory");                      \
    } else {                                                                  \
        asm volatile("s_waitcnt vmcnt(0)" ::: "memory");                      \
    }                                                                         \
    __builtin_amdgcn_s_barrier();                                             \
    __builtin_amdgcn_sched_barrier(0);                                        \
    /* ---- S^T: A = own 32 K rows (global frags), B = both q-tiles ---- */   \
    f32x16 st[2];                                                             \
    _Pragma("unroll")                                                         \
    for (int i = 0; i < 16; i++) { st[0][i] = 0.f; st[1][i] = 0.f; }          \
    __builtin_amdgcn_s_setprio(1);                                            \
    st[0] = __builtin_amdgcn_mfma_f32_32x32x16_f16(kf0, qf[0][0], st[0], 0, 0, 0); \
    st[1] = __builtin_amdgcn_mfma_f32_32x32x16_f16(kf0, qf[1][0], st[1], 0, 0, 0); \
    st[0] = __builtin_amdgcn_mfma_f32_32x32x16_f16(kf1, qf[0][1], st[0], 0, 0, 0); \
    st[1] = __builtin_amdgcn_mfma_f32_32x32x16_f16(kf1, qf[1][1], st[1], 0, 0, 0); \
    st[0] = __builtin_amdgcn_mfma_f32_32x32x16_f16(kf2, qf[0][2], st[0], 0, 0, 0); \
    st[1] = __builtin_amdgcn_mfma_f32_32x32x16_f16(kf2, qf[1][2], st[1], 0, 0, 0); \
    st[0] = __builtin_amdgcn_mfma_f32_32x32x16_f16(kf3, qf[0][3], st[0], 0, 0, 0); \
    st[1] = __builtin_amdgcn_mfma_f32_32x32x16_f16(kf3, qf[1][3], st[1], 0, 0, 0); \
    __builtin_amdgcn_s_setprio(0);                                            \
    /* ---- softmax numerators (in-place exp2) + C->B transform ---- */       \
    union { u32 u[4]; f16x8 v; } pf[2][2];                                    \
    const bool drnd_ = ((S0) == drd_s0);                                      \
    _Pragma("unroll")                                                         \
    for (int qt = 0; qt < 2; qt++) {                                          \
        _Pragma("unroll")                                                     \
        for (int i = 0; i < 16; i++) st[qt][i] = EXP2(st[qt][i]);             \
        if (drnd_ && qt == dqt) {                                             \
            _Pragma("unroll")                                                 \
            for (int i = 0; i < 16; i++) {                                    \
                int row = (i & 3) + 8 * (i >> 2) + 4 * h;                     \
                st[qt][i] = (row == col) ? 0.f : st[qt][i];                   \
            }                                                                 \
        }                                                                     \
        _Pragma("unroll")                                                     \
        for (int i = 0; i < 16; i++) lsum[qt] += st[qt][i];                   \
        u32 P2[8];                                                            \
        _Pragma("unroll")                                                     \
        for (int j = 0; j < 8; j++)                                           \
            P2[j] = pack2(st[qt][2 * j], st[qt][2 * j + 1]);                  \
        plswap(P2[0], P2[2]); plswap(P2[1], P2[3]);                           \
        plswap(P2[4], P2[6]); plswap(P2[5], P2[7]);                           \
        _Pragma("unroll")                                                     \
        for (int jj = 0; jj < 4; jj++) {                                      \
            pf[qt][0].u[jj] = P2[jj];                                         \
            pf[qt][1].u[jj] = P2[4 + jj];                                     \
        }                                                                     \
    }                                                                         \
    /* ---- O^T += V^T . P over own 32 keys (V frags reused across qt) ---- */\
    __builtin_amdgcn_s_setprio(1);                                            \
    _Pragma("unroll")                                                         \
    for (int dt = 0; dt < 2; dt++)                                            \
        _Pragma("unroll")                                                     \
        for (int ks = 0; ks < 2; ks++) {                                      \
            f16x8 vf = *(const f16x8*)((const char*)vfb[ks]                   \
                                       + (P) * 16384 + dt * 8192);            \
            acc[0][dt] = __builtin_amdgcn_mfma_f32_32x32x16_f16(              \
                vf, pf[0][ks].v, acc[0][dt], 0, 0, 0);                        \
            acc[1][dt] = __builtin_amdgcn_mfma_f32_32x32x16_f16(              \
                vf, pf[1][ks].v, acc[1][dt], 0, 0, 0);                        \
        }                                                                     \
    __builtin_amdgcn_s_setprio(0);                                            \
    __builtin_amdgcn_sched_barrier(0);                                        \
    __builtin_amdgcn_s_barrier();                                             \
} while (0)

    #pragma unroll 1
    for (int s0 = 0; s0 < Lsz; s0 += 256) {
        ATTN_ROUND(s0, 0, true);
        ATTN_ROUND(s0 + 128, 1, (s0 + 256 < Lsz));
    }
#undef ATTN_ROUND

    // all waves past the loop before LDS scratch reuse
    __syncthreads();

    // lsum: reduce over half-wave, publish per-wave partial.
    float* Lsp = (float*)(smem + 32768);
    #pragma unroll
    for (int qt = 0; qt < 2; qt++) {
        lsum[qt] += __shfl_xor(lsum[qt], 32);
        if (h == 0) Lsp[w * 64 + qt * 32 + col] = lsum[qt];
    }

    // ---- 4-way split-K merge via reused staging LDS (2 x 16KB slots) ----
    float* Om = (float*)smem;
    if (w == 1 || w == 3) {
        float* og = Om + (w >> 1) * 4096;
        #pragma unroll
        for (int qt = 0; qt < 2; qt++)
            #pragma unroll
            for (int dt = 0; dt < 2; dt++)
                #pragma unroll
                for (int i = 0; i < 16; i++) {
                    int row = (i & 3) + 8 * (i >> 2) + 4 * h;
                    og[(dt * 32 + row) * 64 + qt * 32 + col] = acc[qt][dt][i];
                }
    }
    __syncthreads();
    if (w == 0 || w == 2) {
        const float* og = Om + (w >> 1) * 4096;
        #pragma unroll
        for (int qt = 0; qt < 2; qt++)
            #pragma unroll
            for (int dt = 0; dt < 2; dt++)
                #pragma unroll
                for (int i = 0; i < 16; i++) {
                    int row = (i & 3) + 8 * (i >> 2) + 4 * h;
                    acc[qt][dt][i] += og[(dt * 32 + row) * 64 + qt * 32 + col];
                }
    }
    __syncthreads();
    if (w == 2) {
        #pragma unroll
        for (int qt = 0; qt < 2; qt++)
            #pragma unroll
            for (int dt = 0; dt < 2; dt++)
                #pragma unroll
                for (int i = 0; i < 16; i++) {
                    int row = (i & 3) + 8 * (i >> 2) + 4 * h;
                    Om[(dt * 32 + row) * 64 + qt * 32 + col] = acc[qt][dt][i];
                }
    }
    __syncthreads();
    if (w == 0) {
        #pragma unroll
        for (int qt = 0; qt < 2; qt++)
            #pragma unroll
            for (int dt = 0; dt < 2; dt++)
                #pragma unroll
                for (int i = 0; i < 16; i++) {
                    int row = (i & 3) + 8 * (i >> 2) + 4 * h;
                    acc[qt][dt][i] += Om[(dt * 32 + row) * 64 + qt * 32 + col];
                }
        const int b = bh >> 3, hh = bh & 7;
        #pragma unroll
        for (int qt = 0; qt < 2; qt++) {
            float ls = Lsp[qt * 32 + col] + Lsp[64 + qt * 32 + col]
                     + Lsp[128 + qt * 32 + col] + Lsp[192 + qt * 32 + col];
            const float inv = 1.0f / ls;
            f16* op = ctx + ((size_t)(b * Lsz + q0 + qt * 32 + col)) * DIMsz
                          + hh * 64;
            #pragma unroll
            for (int dt = 0; dt < 2; dt++)
                #pragma unroll
                for (int r4 = 0; r4 < 4; r4++) {
                    f16x4 o;
                    o.x = (f16)(acc[qt][dt][4 * r4 + 0] * inv);
                    o.y = (f16)(acc[qt][dt][4 * r4 + 1] * inv);
                    o.z = (f16)(acc[qt][dt][4 * r4 + 2] * inv);
                    o.w = (f16)(acc[qt][dt][4 * r4 + 3] * inv);
                    *(f16x4*)(op + dt * 32 + 8 * r4 + 4 * h) = o;
                }
        }
    }
}

// ---------------- out-proj MFMA GEMM: out(fp32) = ctx @ wo^T -----------------
__global__ __launch_bounds__(256) void gemm_out_f16(
    const f16* __restrict__ A, const f16* __restrict__ B,
    float* __restrict__ C)
{
    __shared__ f16 Ash[64 * 64];
    __shared__ f16 Bsh[64 * 64];
    const int tid = threadIdx.x;
    const int w = tid >> 6, lane = tid & 63;
    const int quad = lane >> 4, low = lane & 15;
    const int wm = w >> 1, wn = w & 1;
    const int m0 = blockIdx.y * 64, n0 = blockIdx.x * 64;

    f32x4 acc[2][2];
    #pragma unroll
    for (int i = 0; i < 2; i++)
        #pragma unroll
        for (int j = 0; j < 2; j++) acc[i][j] = (f32x4){0.f, 0.f, 0.f, 0.f};

    #pragma unroll 1
    for (int k0 = 0; k0 < DIMsz; k0 += 64) {
        __syncthreads();
        #pragma unroll
        for (int j = 0; j < 2; j++) {
            int t = j * 256 + tid;
            int r = t >> 3, g = t & 7;                 // 64 rows x 8 chunks
            int gc = (g ^ (r & 7)) * 8;
            char* lb = (char*)Ash + (j * 256 + w * 64) * 16;
            gl2lds16(A + (size_t)(m0 + r) * DIMsz + k0 + gc, lb);
            char* lb2 = (char*)Bsh + (j * 256 + w * 64) * 16;
            gl2lds16(B + (size_t)(n0 + r) * DIMsz + k0 + gc, lb2);
        }
        __syncthreads();

        #pragma unroll
        for (int ks2 = 0; ks2 < 2; ks2++) {
            f16x8 af[2], bf[2];
            #pragma unroll
            for (int mt = 0; mt < 2; mt++) {
                int ar = wm * 32 + mt * 16 + low;
                int c = ks2 * 4 + quad;
                af[mt] = *(const f16x8*)&Ash[ar * 64 + ((c ^ (ar & 7)) << 3)];
            }
            #pragma unroll
            for (int nt = 0; nt < 2; nt++) {
                int br = wn * 32 + nt * 16 + low;
                int c = ks2 * 4 + quad;
                bf[nt] = *(const f16x8*)&Bsh[br * 64 + ((c ^ (br & 7)) << 3)];
            }
            #pragma unroll
            for (int mt = 0; mt < 2; mt++)
                #pragma unroll
                for (int nt = 0; nt < 2; nt++)
                    acc[mt][nt] = __builtin_amdgcn_mfma_f32_16x16x32_f16(
                        af[mt], bf[nt], acc[mt][nt], 0, 0, 0);
        }
    }

    #pragma unroll
    for (int mt = 0; mt < 2; mt++)
        #pragma unroll
        for (int r = 0; r < 4; r++) {
            int m = m0 + wm * 32 + mt * 16 + quad * 4 + r;
            #pragma unroll
            for (int nt = 0; nt < 2; nt++) {
                int n = n0 + wn * 32 + nt * 16 + low;
                C[(size_t)m * DIMsz + n] = acc[mt][nt][r];
            }
        }
}

extern "C" void kernel_launch(void* const* d_in, const int* in_sizes, int n_in,
                              void* d_out, int out_size, void* d_ws, size_t ws_size,
                              hipStream_t stream) {
    const float* x  = (const float*)d_in[0];
    const float* wq = (const float*)d_in[1];
    const float* wk = (const float*)d_in[2];
    const float* wv = (const float*)d_in[3];
    const float* wo = (const float*)d_in[4];
    float* out = (float*)d_out;

    const size_t NTOK = (size_t)Bsz * Lsz;   // 8192
    const size_t XSZ  = NTOK * DIMsz;        // 4,194,304

    f16* xh   = (f16*)d_ws;                  // 8 MB
    f16* w3h  = xh + XSZ;                    // 1.5 MB  [1536][512]
    f16* woh  = w3h + 3 * 262144;            // 0.5 MB
    f16* qh   = woh + 262144;                // 8 MB [bh][l][d] (scale*log2e)
    f16* kh   = qh + XSZ;                    // 8 MB [bh][l][d]
    f16* vth  = kh + XSZ;                    // 8 MB [bh][d][l]
    f16* ctxh = vth + XSZ;                   // 8 MB [b*l][512]

    pack_f16<<<5120, 256, 0, stream>>>(x, wq, wk, wv, wo, xh, w3h, woh);

    dim3 g1(1536 / 128, NTOK / 128);         // (12, 64)
    gemm_qkv_f16<<<g1, 256, 0, stream>>>(xh, w3h, qh, kh, vth);

    dim3 g2(Bsz * Hsz, Lsz / 64);            // (32 bh, 32 qb) — bh fastest
    attn_mfma<<<g2, 256, 0, stream>>>(qh, kh, vth, ctxh);

    dim3 g3(DIMsz / 64, NTOK / 64);          // (8, 128)
    gemm_out_f16<<<g3, 256, 0, stream>>>(ctxh, woh, out);
}

// Round 7
// 167.427 us; speedup vs baseline: 1.3638x; 1.3638x over previous
//
#include <hip/hip_runtime.h>
#include <hip/hip_bf16.h>

// B=4, L=2048, DIM=512, H=8, D=64, fp32 in/out.
// pack fp32->fp16 (log2e folded into wq) -> fused QKV MFMA GEMM (BK=64, V^T
// via in-LDS transpose epilogue) -> 32x32x16-MFMA flash attn (64q/wave,
// 4-way key-split waves, 128-key rounds, DOUBLE-BUFFERED gl2lds staging with
// counted vmcnt + raw barriers [T3/T4], setprio around MFMA [T5],
// permlane32_swap P-transform) -> out-proj MFMA GEMM (128^2 tile, same
// proven mainloop as gemm_qkv).
// NOTE: global_load_lds imm offset applies to the GLOBAL address only; the
// LDS dest is always M0 + lane*16 -> multi-call staging must bump BOTH ptrs.
// NOTE: attn main loop uses raw s_barrier + asm s_waitcnt vmcnt(8): prefetch
// for round s+1 stays in flight across the barrier (hipcc __syncthreads
// would drain vmcnt(0) and expose the staging latency every round).
// LESSON (R3-R6): every attempt to shrink attn LDS below the full K+V double
// buffer (single-buffered K with mid-round staging, qt-split, K-from-global)
// produced ~30MB anomalous HBM writes + 2x slowdown. The R1 schedule below
// (64KB LDS, 2 blocks/CU, counted vmcnt) is the best measured: 56us.

#define Bsz 4
#define Lsz 2048
#define DIMsz 512
#define Hsz 8
#define Dsz 64

typedef _Float16 f16;
typedef __attribute__((ext_vector_type(8))) _Float16 f16x8;
typedef __attribute__((ext_vector_type(4))) _Float16 f16x4;
typedef __attribute__((ext_vector_type(2))) __fp16 fp16x2;  // builtin ret type
typedef __attribute__((ext_vector_type(4))) float f32x4;
typedef __attribute__((ext_vector_type(16))) float f32x16;
typedef unsigned int u32;
typedef __attribute__((ext_vector_type(2))) unsigned int u32x2;

#if __has_builtin(__builtin_amdgcn_exp2f)
#define EXP2(x) __builtin_amdgcn_exp2f(x)
#else
#define EXP2(x) __expf(0.6931471805599453f * (x))
#endif

__device__ __forceinline__ u32 pack2(float a, float b) {
#if __has_builtin(__builtin_amdgcn_cvt_pkrtz)
    fp16x2 h = __builtin_amdgcn_cvt_pkrtz(a, b);
    return __builtin_bit_cast(u32, h);
#else
    fp16x2 h; h.x = (__fp16)a; h.y = (__fp16)b;
    return __builtin_bit_cast(u32, h);
#endif
}

// Cross-half exchange for the 32x32 C->B P-transform.
#if __has_builtin(__builtin_amdgcn_permlane32_swap)
__device__ __forceinline__ void plswap(u32& a, u32& b) {
    u32x2 r = __builtin_amdgcn_permlane32_swap(a, b, false, false);
    a = r.x; b = r.y;
}
#else
__device__ __forceinline__ void plswap(u32& a, u32& b) {
    u32 sa = (u32)__shfl_xor((int)a, 32);
    u32 sb = (u32)__shfl_xor((int)b, 32);
    bool hi = (threadIdx.x & 32) != 0;
    u32 na = hi ? sb : a;
    u32 nb = hi ? b : sa;
    a = na; b = nb;
}
#endif

__device__ __forceinline__ void gl2lds16(const void* g, void* l) {
    __builtin_amdgcn_global_load_lds(
        (const __attribute__((address_space(1))) u32*)g,
        (__attribute__((address_space(3))) u32*)l, 16, 0, 0);
}

// ---------------- pack: fp32 -> fp16 ----------------------------------------
__global__ __launch_bounds__(256) void pack_f16(
    const float* __restrict__ x, const float* __restrict__ wq,
    const float* __restrict__ wk, const float* __restrict__ wv,
    const float* __restrict__ wo,
    f16* __restrict__ xh, f16* __restrict__ w3h, f16* __restrict__ woh)
{
    int bx = blockIdx.x, seg, blk;
    if (bx < 4096) { seg = 0; blk = bx; }
    else { seg = 1 + ((bx - 4096) >> 8); blk = (bx - 4096) & 255; }
    const float* s; f16* d; float sc = 1.0f;
    switch (seg) {
        case 0: s = x;  d = xh;            break;
        case 1: s = wq; d = w3h;           sc = 0.18033688011112042f; break;
        case 2: s = wk; d = w3h + 262144;  break;
        case 3: s = wv; d = w3h + 524288;  break;
        default: s = wo; d = woh;          break;
    }
    int i = (blk * 256 + threadIdx.x) * 4;
    float4 v = *(const float4*)(s + i);
    f16x4 o;
    o.x = (f16)(v.x * sc); o.y = (f16)(v.y * sc);
    o.z = (f16)(v.z * sc); o.w = (f16)(v.w * sc);
    *(f16x4*)(d + i) = o;
}

// ---------------- fused QKV MFMA GEMM (BK=64) --------------------------------
__global__ __launch_bounds__(256) void gemm_qkv_f16(
    const f16* __restrict__ A, const f16* __restrict__ B,
    f16* __restrict__ qh, f16* __restrict__ kh, f16* __restrict__ vth)
{
    __shared__ __align__(16) char smem[32768];   // A 16K | B 16K ; Tv reuse
    f16* Ash = (f16*)smem;
    f16* Bsh = (f16*)(smem + 16384);

    const int tid = threadIdx.x;
    const int w = tid >> 6, lane = tid & 63;
    const int quad = lane >> 4, low = lane & 15;
    const int wm = w >> 1, wn = w & 1;
    const int m0 = blockIdx.y * 128, n0 = blockIdx.x * 128;

    f32x4 acc[4][4];
    #pragma unroll
    for (int i = 0; i < 4; i++)
        #pragma unroll
        for (int j = 0; j < 4; j++) acc[i][j] = (f32x4){0.f, 0.f, 0.f, 0.f};

    #pragma unroll 1
    for (int k0 = 0; k0 < DIMsz; k0 += 64) {
        __syncthreads();
        #pragma unroll
        for (int j = 0; j < 4; j++) {
            int t = j * 256 + tid;
            int r = t >> 3, g = t & 7;                 // 128 rows x 8 chunks
            int gc = (g ^ (r & 7)) * 8;
            char* lb = (char*)Ash + (j * 256 + w * 64) * 16;
            gl2lds16(A + (size_t)(m0 + r) * DIMsz + k0 + gc, lb);
            char* lb2 = (char*)Bsh + (j * 256 + w * 64) * 16;
            gl2lds16(B + (size_t)(n0 + r) * DIMsz + k0 + gc, lb2);
        }
        __syncthreads();

        #pragma unroll
        for (int ks2 = 0; ks2 < 2; ks2++) {
            f16x8 af[4], bf[4];
            #pragma unroll
            for (int mt = 0; mt < 4; mt++) {
                int ar = wm * 64 + mt * 16 + low;
                int c = ks2 * 4 + quad;
                af[mt] = *(const f16x8*)&Ash[ar * 64 + ((c ^ (ar & 7)) << 3)];
            }
            #pragma unroll
            for (int nt = 0; nt < 4; nt++) {
                int br = wn * 64 + nt * 16 + low;
                int c = ks2 * 4 + quad;
                bf[nt] = *(const f16x8*)&Bsh[br * 64 + ((c ^ (br & 7)) << 3)];
            }
            #pragma unroll
            for (int mt = 0; mt < 4; mt++)
                #pragma unroll
                for (int nt = 0; nt < 4; nt++)
                    acc[mt][nt] = __builtin_amdgcn_mfma_f32_16x16x32_f16(
                        af[mt], bf[nt], acc[mt][nt], 0, 0, 0);
        }
    }

    const int proj = n0 >> 9;                 // uniform per block
    if (proj < 2) {
        f16* dst = (proj == 0) ? qh : kh;
        #pragma unroll
        for (int nt = 0; nt < 4; nt++) {
            int n = n0 + wn * 64 + nt * 16 + low;
            int c = n & 511, h = c >> 6, d = c & 63;
            #pragma unroll
            for (int mt = 0; mt < 4; mt++)
                #pragma unroll
                for (int r = 0; r < 4; r++) {
                    int m = m0 + wm * 64 + mt * 16 + quad * 4 + r;
                    int b_ = m >> 11, l = m & (Lsz - 1);
                    size_t bh = (size_t)(b_ * Hsz + h);
                    dst[(bh * Lsz + l) * Dsz + d] = (f16)acc[mt][nt][r];
                }
        }
    } else {
        // v: transpose per head through LDS, then coalesced stores
        const int hb = (n0 & 511) >> 6;
        f16* Tv = (f16*)smem;                 // [64 d][136]
        const int b_ = m0 >> 11, l0 = m0 & (Lsz - 1);
        #pragma unroll 1
        for (int hs = 0; hs < 2; hs++) {
            __syncthreads();
            if (wn == hs) {
                #pragma unroll
                for (int nt = 0; nt < 4; nt++) {
                    int d = nt * 16 + low;
                    #pragma unroll
                    for (int mt = 0; mt < 4; mt++)
                        #pragma unroll
                        for (int r = 0; r < 4; r++) {
                            int l = wm * 64 + mt * 16 + quad * 4 + r;
                            Tv[d * 136 + l] = (f16)acc[mt][nt][r];
                        }
                }
            }
            __syncthreads();
            int d = tid >> 2, seg = tid & 3;
            size_t bh = (size_t)(b_ * Hsz + hb + hs);
            f16* dstp = vth + (bh * 64 + d) * (size_t)Lsz + l0 + seg * 32;
            const f16* srcp = Tv + d * 136 + seg * 32;
            #pragma unroll
            for (int j = 0; j < 4; j++)
                *(f16x8*)(dstp + j * 8) = *(const f16x8*)(srcp + j * 8);
        }
    }
}

// ---------------- MFMA flash attention (64q/wave, 4-way key split) -----------
// grid (B*H=32 fastest -> XCD locality, L/64=32), block 256 = 4 waves = 64 q.
// Each round stages 128 keys; wave w owns keys w*32..+31 and computes them
// against ALL 64 q (2 B-operand q-tiles) -> K/V frag reads amortize 2x.
// T3/T4: K/V staging is double-buffered (2x32KB); round s issues round s+1's
// 8 global_load_lds, then waits s_waitcnt vmcnt(8) (own round-s loads done,
// prefetch stays in flight) + raw s_barrier. vmcnt(0) only on last round.
// 4-way split-K O/lsum merge via reused staging LDS at the end.
__global__ __launch_bounds__(256, 2) void attn_mfma(
    const f16* __restrict__ q, const f16* __restrict__ k,
    const f16* __restrict__ vt, f16* __restrict__ ctx)
{
    __shared__ __align__(16) char smem[65536];   // 2x (Ks 16K | Vs 16K); Om/Ls reuse

    const int tid = threadIdx.x;
    const int w = tid >> 6, lane = tid & 63;
    const int col = lane & 31;
    const int h = lane >> 5;
    const int bh = blockIdx.x;        // fastest -> 4 heads per XCD
    const int qb = blockIdx.y;
    const int q0 = qb * 64;
    const size_t kvb = (size_t)bh * Lsz;

    f16* Ks = (f16*)smem;             // buf0 [128 key][64 d], 8-chunk XOR swz
    f16* Vs = (f16*)(smem + 16384);   // buf0 [64 d][128 key], 16-chunk XOR swz

    // Q B-frags for 2 q-tiles: B[k=d][n=q], lane n=col, k = s*16 + h*8 + j
    f16x8 qf[2][4];
    #pragma unroll
    for (int qt = 0; qt < 2; qt++)
        #pragma unroll
        for (int s = 0; s < 4; s++)
            qf[qt][s] = *(const f16x8*)(q + (kvb + q0 + qt * 32 + col) * Dsz
                                          + s * 16 + h * 8);
    // Force q loads to retire BEFORE manual vmcnt bookkeeping starts, so the
    // compiler never needs to insert a vmcnt wait for qf inside the loop.
    #pragma unroll
    for (int qt = 0; qt < 2; qt++)
        #pragma unroll
        for (int s = 0; s < 4; s++)
            asm volatile("" :: "v"(qf[qt][s]));

    // staging source base pointers (lane-specific, bumped per round)
    const f16* kp; const f16* vp;
    {
        int rk_ = tid >> 3, gk = tid & 7;         // kp covers rows 0..31
        kp = k + (kvb + rk_) * Dsz + ((gk ^ (rk_ & 7)) << 3);
        int rv = tid >> 4, gv = tid & 15;         // vp covers rows 0..15
        vp = vt + ((size_t)bh * Dsz + rv) * Lsz + ((gv ^ (rv & 15)) << 3);
    }
    char* kl = (char*)smem + w * 1024;            // wave-uniform LDS dests
    char* vl = (char*)smem + 16384 + w * 1024;

    // loop-invariant LDS frag pointers (buf0; +32768 selects buf1)
    const int rk = w * 32 + col;                  // wave's key rows
    const f16* kfp[4];
    #pragma unroll
    for (int s = 0; s < 4; s++)
        kfp[s] = Ks + rk * 64 + (((s * 2 + h) ^ (rk & 7)) << 3);
    const f16* vfp[2][2];
    #pragma unroll
    for (int dt = 0; dt < 2; dt++)
        #pragma unroll
        for (int ks = 0; ks < 2; ks++) {
            int rv = dt * 32 + col, cv = w * 4 + ks * 2 + h;
            vfp[dt][ks] = Vs + rv * 128 + ((cv ^ (rv & 15)) << 3);
        }

    f32x16 acc[2][2];                 // O^T partial [qt][dt], cols = q
    #pragma unroll
    for (int qt = 0; qt < 2; qt++)
        #pragma unroll
        for (int dt = 0; dt < 2; dt++)
            #pragma unroll
            for (int i = 0; i < 16; i++) acc[qt][dt][i] = 0.f;
    float lsum[2] = {0.f, 0.f};

    const int drd_s0 = (qb >> 1) * 128;           // round containing the diag
    const int dqt = w - (qb & 1) * 2;             // qt this wave diag-masks

    // prologue: stage round 0 into buf0
    gl2lds16(kp,        kl);
    gl2lds16(kp + 2048, kl + 4096);
    gl2lds16(kp + 4096, kl + 8192);
    gl2lds16(kp + 6144, kl + 12288);
    gl2lds16(vp,            vl);
    gl2lds16(vp + 16 * Lsz, vl + 4096);
    gl2lds16(vp + 32 * Lsz, vl + 8192);
    gl2lds16(vp + 48 * Lsz, vl + 12288);
    kp += 128 * Dsz;
    vp += 128;

#define ATTN_ROUND(S0, P, PRE) do {                                           \
    const int bufoff_ = (P) * 32768;                                          \
    if (PRE) {                                                                \
        const int nx_ = ((P) ^ 1) * 32768;                                    \
        gl2lds16(kp,        kl + nx_);                                        \
        gl2lds16(kp + 2048, kl + nx_ + 4096);                                 \
        gl2lds16(kp + 4096, kl + nx_ + 8192);                                 \
        gl2lds16(kp + 6144, kl + nx_ + 12288);                                \
        gl2lds16(vp,            vl + nx_);                                    \
        gl2lds16(vp + 16 * Lsz, vl + nx_ + 4096);                             \
        gl2lds16(vp + 32 * Lsz, vl + nx_ + 8192);                             \
        gl2lds16(vp + 48 * Lsz, vl + nx_ + 12288);                            \
        kp += 128 * Dsz;                                                      \
        vp += 128;                                                            \
        asm volatile("s_waitcnt vmcnt(8)" ::: "memory");                      \
    } else {                                                                  \
        asm volatile("s_waitcnt vmcnt(0)" ::: "memory");                      \
    }                                                                         \
    __builtin_amdgcn_s_barrier();                                             \
    __builtin_amdgcn_sched_barrier(0);                                        \
    /* ---- S^T: A = own 32 K rows, B = both q-tiles; 4 k-steps over d ---- */\
    f32x16 st[2];                                                             \
    _Pragma("unroll")                                                         \
    for (int i = 0; i < 16; i++) { st[0][i] = 0.f; st[1][i] = 0.f; }          \
    __builtin_amdgcn_s_setprio(1);                                            \
    _Pragma("unroll")                                                         \
    for (int s = 0; s < 4; s++) {                                             \
        f16x8 kf = *(const f16x8*)((const char*)kfp[s] + bufoff_);            \
        st[0] = __builtin_amdgcn_mfma_f32_32x32x16_f16(kf, qf[0][s],          \
                                                       st[0], 0, 0, 0);       \
        st[1] = __builtin_amdgcn_mfma_f32_32x32x16_f16(kf, qf[1][s],          \
                                                       st[1], 0, 0, 0);       \
    }                                                                         \
    __builtin_amdgcn_s_setprio(0);                                            \
    /* ---- softmax numerators + C->B transform per q-tile ---- */            \
    union { u32 u[4]; f16x8 v; } pf[2][2];                                    \
    const bool drnd_ = ((S0) == drd_s0);                                      \
    _Pragma("unroll")                                                         \
    for (int qt = 0; qt < 2; qt++) {                                          \
        float pv[16];                                                         \
        _Pragma("unroll")                                                     \
        for (int i = 0; i < 16; i++) pv[i] = EXP2(st[qt][i]);                 \
        if (drnd_ && qt == dqt) {                                             \
            _Pragma("unroll")                                                 \
            for (int i = 0; i < 16; i++) {                                    \
                int row = (i & 3) + 8 * (i >> 2) + 4 * h;                     \
                pv[i] = (row == col) ? 0.f : pv[i];                           \
            }                                                                 \
        }                                                                     \
        _Pragma("unroll")                                                     \
        for (int i = 0; i < 16; i++) lsum[qt] += pv[i];                       \
        u32 P2[8];                                                            \
        _Pragma("unroll")                                                     \
        for (int j = 0; j < 8; j++)                                           \
            P2[j] = pack2(pv[2 * j], pv[2 * j + 1]);                          \
        plswap(P2[0], P2[2]); plswap(P2[1], P2[3]);                           \
        plswap(P2[4], P2[6]); plswap(P2[5], P2[7]);                           \
        _Pragma("unroll")                                                     \
        for (int jj = 0; jj < 4; jj++) {                                      \
            pf[qt][0].u[jj] = P2[jj];                                         \
            pf[qt][1].u[jj] = P2[4 + jj];                                     \
        }                                                                     \
    }                                                                         \
    /* ---- O^T += V^T . P over own 32 keys (V frags reused across qt) ---- */\
    __builtin_amdgcn_s_setprio(1);                                            \
    _Pragma("unroll")                                                         \
    for (int dt = 0; dt < 2; dt++)                                            \
        _Pragma("unroll")                                                     \
        for (int ks = 0; ks < 2; ks++) {                                      \
            f16x8 vf = *(const f16x8*)((const char*)vfp[dt][ks] + bufoff_);   \
            acc[0][dt] = __builtin_amdgcn_mfma_f32_32x32x16_f16(              \
                vf, pf[0][ks].v, acc[0][dt], 0, 0, 0);                        \
            acc[1][dt] = __builtin_amdgcn_mfma_f32_32x32x16_f16(              \
                vf, pf[1][ks].v, acc[1][dt], 0, 0, 0);                        \
        }                                                                     \
    __builtin_amdgcn_s_setprio(0);                                            \
    __builtin_amdgcn_sched_barrier(0);                                        \
    __builtin_amdgcn_s_barrier();                                             \
} while (0)

    #pragma unroll 1
    for (int s0 = 0; s0 < Lsz; s0 += 256) {
        ATTN_ROUND(s0, 0, true);
        ATTN_ROUND(s0 + 128, 1, (s0 + 256 < Lsz));
    }
#undef ATTN_ROUND

    // lsum: reduce over half-wave, publish per-wave partial.
    // Ls lives in the tail of buf1's Vs region (dead after the last round).
    float* Lsp = (float*)(smem + 49152);
    #pragma unroll
    for (int qt = 0; qt < 2; qt++) {
        lsum[qt] += __shfl_xor(lsum[qt], 32);
        if (h == 0) Lsp[w * 64 + qt * 32 + col] = lsum[qt];
    }

    // ---- 4-way split-K merge via reused staging LDS (2 x 16KB slots) ----
    float* Om = (float*)smem;
    __syncthreads();
    if (w == 1 || w == 3) {
        float* og = Om + (w >> 1) * 4096;
        #pragma unroll
        for (int qt = 0; qt < 2; qt++)
            #pragma unroll
            for (int dt = 0; dt < 2; dt++)
                #pragma unroll
                for (int i = 0; i < 16; i++) {
                    int row = (i & 3) + 8 * (i >> 2) + 4 * h;
                    og[(dt * 32 + row) * 64 + qt * 32 + col] = acc[qt][dt][i];
                }
    }
    __syncthreads();
    if (w == 0 || w == 2) {
        const float* og = Om + (w >> 1) * 4096;
        #pragma unroll
        for (int qt = 0; qt < 2; qt++)
            #pragma unroll
            for (int dt = 0; dt < 2; dt++)
                #pragma unroll
                for (int i = 0; i < 16; i++) {
                    int row = (i & 3) + 8 * (i >> 2) + 4 * h;
                    acc[qt][dt][i] += og[(dt * 32 + row) * 64 + qt * 32 + col];
                }
    }
    __syncthreads();
    if (w == 2) {
        #pragma unroll
        for (int qt = 0; qt < 2; qt++)
            #pragma unroll
            for (int dt = 0; dt < 2; dt++)
                #pragma unroll
                for (int i = 0; i < 16; i++) {
                    int row = (i & 3) + 8 * (i >> 2) + 4 * h;
                    Om[(dt * 32 + row) * 64 + qt * 32 + col] = acc[qt][dt][i];
                }
    }
    __syncthreads();
    if (w == 0) {
        #pragma unroll
        for (int qt = 0; qt < 2; qt++)
            #pragma unroll
            for (int dt = 0; dt < 2; dt++)
                #pragma unroll
                for (int i = 0; i < 16; i++) {
                    int row = (i & 3) + 8 * (i >> 2) + 4 * h;
                    acc[qt][dt][i] += Om[(dt * 32 + row) * 64 + qt * 32 + col];
                }
        const int b = bh >> 3, hh = bh & 7;
        #pragma unroll
        for (int qt = 0; qt < 2; qt++) {
            float ls = Lsp[qt * 32 + col] + Lsp[64 + qt * 32 + col]
                     + Lsp[128 + qt * 32 + col] + Lsp[192 + qt * 32 + col];
            const float inv = 1.0f / ls;
            f16* op = ctx + ((size_t)(b * Lsz + q0 + qt * 32 + col)) * DIMsz
                          + hh * 64;
            #pragma unroll
            for (int dt = 0; dt < 2; dt++)
                #pragma unroll
                for (int r4 = 0; r4 < 4; r4++) {
                    f16x4 o;
                    o.x = (f16)(acc[qt][dt][4 * r4 + 0] * inv);
                    o.y = (f16)(acc[qt][dt][4 * r4 + 1] * inv);
                    o.z = (f16)(acc[qt][dt][4 * r4 + 2] * inv);
                    o.w = (f16)(acc[qt][dt][4 * r4 + 3] * inv);
                    *(f16x4*)(op + dt * 32 + 8 * r4 + 4 * h) = o;
                }
        }
    }
}

// ---------------- out-proj MFMA GEMM: out(fp32) = ctx @ wo^T -----------------
// 128^2 tile, BK=64, identical mainloop geometry to gemm_qkv (proven).
// grid (512/128=4, 8192/128=64) = 256 blocks.
__global__ __launch_bounds__(256) void gemm_out_f16(
    const f16* __restrict__ A, const f16* __restrict__ B,
    float* __restrict__ C)
{
    __shared__ __align__(16) char smem[32768];   // A 16K | B 16K
    f16* Ash = (f16*)smem;
    f16* Bsh = (f16*)(smem + 16384);

    const int tid = threadIdx.x;
    const int w = tid >> 6, lane = tid & 63;
    const int quad = lane >> 4, low = lane & 15;
    const int wm = w >> 1, wn = w & 1;
    const int m0 = blockIdx.y * 128, n0 = blockIdx.x * 128;

    f32x4 acc[4][4];
    #pragma unroll
    for (int i = 0; i < 4; i++)
        #pragma unroll
        for (int j = 0; j < 4; j++) acc[i][j] = (f32x4){0.f, 0.f, 0.f, 0.f};

    #pragma unroll 1
    for (int k0 = 0; k0 < DIMsz; k0 += 64) {
        __syncthreads();
        #pragma unroll
        for (int j = 0; j < 4; j++) {
            int t = j * 256 + tid;
            int r = t >> 3, g = t & 7;                 // 128 rows x 8 chunks
            int gc = (g ^ (r & 7)) * 8;
            char* lb = (char*)Ash + (j * 256 + w * 64) * 16;
            gl2lds16(A + (size_t)(m0 + r) * DIMsz + k0 + gc, lb);
            char* lb2 = (char*)Bsh + (j * 256 + w * 64) * 16;
            gl2lds16(B + (size_t)(n0 + r) * DIMsz + k0 + gc, lb2);
        }
        __syncthreads();

        #pragma unroll
        for (int ks2 = 0; ks2 < 2; ks2++) {
            f16x8 af[4], bf[4];
            #pragma unroll
            for (int mt = 0; mt < 4; mt++) {
                int ar = wm * 64 + mt * 16 + low;
                int c = ks2 * 4 + quad;
                af[mt] = *(const f16x8*)&Ash[ar * 64 + ((c ^ (ar & 7)) << 3)];
            }
            #pragma unroll
            for (int nt = 0; nt < 4; nt++) {
                int br = wn * 64 + nt * 16 + low;
                int c = ks2 * 4 + quad;
                bf[nt] = *(const f16x8*)&Bsh[br * 64 + ((c ^ (br & 7)) << 3)];
            }
            #pragma unroll
            for (int mt = 0; mt < 4; mt++)
                #pragma unroll
                for (int nt = 0; nt < 4; nt++)
                    acc[mt][nt] = __builtin_amdgcn_mfma_f32_16x16x32_f16(
                        af[mt], bf[nt], acc[mt][nt], 0, 0, 0);
        }
    }

    #pragma unroll
    for (int mt = 0; mt < 4; mt++)
        #pragma unroll
        for (int r = 0; r < 4; r++) {
            int m = m0 + wm * 64 + mt * 16 + quad * 4 + r;
            #pragma unroll
            for (int nt = 0; nt < 4; nt++) {
                int n = n0 + wn * 64 + nt * 16 + low;
                C[(size_t)m * DIMsz + n] = acc[mt][nt][r];
            }
        }
}

extern "C" void kernel_launch(void* const* d_in, const int* in_sizes, int n_in,
                              void* d_out, int out_size, void* d_ws, size_t ws_size,
                              hipStream_t stream) {
    const float* x  = (const float*)d_in[0];
    const float* wq = (const float*)d_in[1];
    const float* wk = (const float*)d_in[2];
    const float* wv = (const float*)d_in[3];
    const float* wo = (const float*)d_in[4];
    float* out = (float*)d_out;

    const size_t NTOK = (size_t)Bsz * Lsz;   // 8192
    const size_t XSZ  = NTOK * DIMsz;        // 4,194,304

    f16* xh   = (f16*)d_ws;                  // 8 MB
    f16* w3h  = xh + XSZ;                    // 1.5 MB  [1536][512]
    f16* woh  = w3h + 3 * 262144;            // 0.5 MB
    f16* qh   = woh + 262144;                // 8 MB [bh][l][d] (scale*log2e)
    f16* kh   = qh + XSZ;                    // 8 MB [bh][l][d]
    f16* vth  = kh + XSZ;                    // 8 MB [bh][d][l]
    f16* ctxh = vth + XSZ;                   // 8 MB [b*l][512]

    pack_f16<<<5120, 256, 0, stream>>>(x, wq, wk, wv, wo, xh, w3h, woh);

    dim3 g1(1536 / 128, NTOK / 128);         // (12, 64)
    gemm_qkv_f16<<<g1, 256, 0, stream>>>(xh, w3h, qh, kh, vth);

    dim3 g2(Bsz * Hsz, Lsz / 64);            // (32 bh, 32 qb) — bh fastest
    attn_mfma<<<g2, 256, 0, stream>>>(qh, kh, vth, ctxh);

    dim3 g3(DIMsz / 128, NTOK / 128);        // (4, 64) — 128^2 tiles
    gemm_out_f16<<<g3, 256, 0, stream>>>(ctxh, woh, out);
}

// Round 8
// 162.492 us; speedup vs baseline: 1.4052x; 1.0304x over previous
//
#include <hip/hip_runtime.h>
#include <hip/hip_bf16.h>

// B=4, L=2048, DIM=512, H=8, D=64, fp32 in/out.
// pack fp32->fp16 (log2e folded into wq) -> fused QKV MFMA GEMM (BK=64, V^T
// via in-LDS transpose epilogue) -> 32x32x16-MFMA flash attn (64-key rounds,
// 4 waves = 2-way key split x 2-way q split, 32 keys x 32 q per wave,
// K+V DOUBLE-BUFFERED gl2lds with counted vmcnt + 2 raw barriers/round
// [T3/T4, 33.8KB LDS -> 3 blocks/CU], setprio [T5], permlane32_swap
// P-transform) -> out-proj MFMA GEMM (64^2).
// NOTE: global_load_lds imm offset applies to the GLOBAL address only; the
// LDS dest is always M0 + lane*16 -> multi-call staging must bump BOTH ptrs.
// NOTE: main loop uses raw s_barrier + asm s_waitcnt vmcnt(4): the 4
// prefetch loads for round r+1 stay in flight across the barrier.
// LESSON (R3-R6): mid-round staging / 3-barrier variants spill (~30MB
// anomalous HBM writes, 2x slower). This keeps R1's exact 2-barrier
// schedule; only the wave->work mapping and round size change.

#define Bsz 4
#define Lsz 2048
#define DIMsz 512
#define Hsz 8
#define Dsz 64

typedef _Float16 f16;
typedef __attribute__((ext_vector_type(8))) _Float16 f16x8;
typedef __attribute__((ext_vector_type(4))) _Float16 f16x4;
typedef __attribute__((ext_vector_type(2))) __fp16 fp16x2;  // builtin ret type
typedef __attribute__((ext_vector_type(4))) float f32x4;
typedef __attribute__((ext_vector_type(16))) float f32x16;
typedef unsigned int u32;
typedef __attribute__((ext_vector_type(2))) unsigned int u32x2;

#if __has_builtin(__builtin_amdgcn_exp2f)
#define EXP2(x) __builtin_amdgcn_exp2f(x)
#else
#define EXP2(x) __expf(0.6931471805599453f * (x))
#endif

__device__ __forceinline__ u32 pack2(float a, float b) {
#if __has_builtin(__builtin_amdgcn_cvt_pkrtz)
    fp16x2 h = __builtin_amdgcn_cvt_pkrtz(a, b);
    return __builtin_bit_cast(u32, h);
#else
    fp16x2 h; h.x = (__fp16)a; h.y = (__fp16)b;
    return __builtin_bit_cast(u32, h);
#endif
}

// Cross-half exchange for the 32x32 C->B P-transform.
#if __has_builtin(__builtin_amdgcn_permlane32_swap)
__device__ __forceinline__ void plswap(u32& a, u32& b) {
    u32x2 r = __builtin_amdgcn_permlane32_swap(a, b, false, false);
    a = r.x; b = r.y;
}
#else
__device__ __forceinline__ void plswap(u32& a, u32& b) {
    u32 sa = (u32)__shfl_xor((int)a, 32);
    u32 sb = (u32)__shfl_xor((int)b, 32);
    bool hi = (threadIdx.x & 32) != 0;
    u32 na = hi ? sb : a;
    u32 nb = hi ? b : sa;
    a = na; b = nb;
}
#endif

__device__ __forceinline__ void gl2lds16(const void* g, void* l) {
    __builtin_amdgcn_global_load_lds(
        (const __attribute__((address_space(1))) u32*)g,
        (__attribute__((address_space(3))) u32*)l, 16, 0, 0);
}

// ---------------- pack: fp32 -> fp16 ----------------------------------------
__global__ __launch_bounds__(256) void pack_f16(
    const float* __restrict__ x, const float* __restrict__ wq,
    const float* __restrict__ wk, const float* __restrict__ wv,
    const float* __restrict__ wo,
    f16* __restrict__ xh, f16* __restrict__ w3h, f16* __restrict__ woh)
{
    int bx = blockIdx.x, seg, blk;
    if (bx < 4096) { seg = 0; blk = bx; }
    else { seg = 1 + ((bx - 4096) >> 8); blk = (bx - 4096) & 255; }
    const float* s; f16* d; float sc = 1.0f;
    switch (seg) {
        case 0: s = x;  d = xh;            break;
        case 1: s = wq; d = w3h;           sc = 0.18033688011112042f; break;
        case 2: s = wk; d = w3h + 262144;  break;
        case 3: s = wv; d = w3h + 524288;  break;
        default: s = wo; d = woh;          break;
    }
    int i = (blk * 256 + threadIdx.x) * 4;
    float4 v = *(const float4*)(s + i);
    f16x4 o;
    o.x = (f16)(v.x * sc); o.y = (f16)(v.y * sc);
    o.z = (f16)(v.z * sc); o.w = (f16)(v.w * sc);
    *(f16x4*)(d + i) = o;
}

// ---------------- fused QKV MFMA GEMM (BK=64) --------------------------------
__global__ __launch_bounds__(256) void gemm_qkv_f16(
    const f16* __restrict__ A, const f16* __restrict__ B,
    f16* __restrict__ qh, f16* __restrict__ kh, f16* __restrict__ vth)
{
    __shared__ __align__(16) char smem[32768];   // A 16K | B 16K ; Tv reuse
    f16* Ash = (f16*)smem;
    f16* Bsh = (f16*)(smem + 16384);

    const int tid = threadIdx.x;
    const int w = tid >> 6, lane = tid & 63;
    const int quad = lane >> 4, low = lane & 15;
    const int wm = w >> 1, wn = w & 1;
    const int m0 = blockIdx.y * 128, n0 = blockIdx.x * 128;

    f32x4 acc[4][4];
    #pragma unroll
    for (int i = 0; i < 4; i++)
        #pragma unroll
        for (int j = 0; j < 4; j++) acc[i][j] = (f32x4){0.f, 0.f, 0.f, 0.f};

    #pragma unroll 1
    for (int k0 = 0; k0 < DIMsz; k0 += 64) {
        __syncthreads();
        #pragma unroll
        for (int j = 0; j < 4; j++) {
            int t = j * 256 + tid;
            int r = t >> 3, g = t & 7;                 // 128 rows x 8 chunks
            int gc = (g ^ (r & 7)) * 8;
            char* lb = (char*)Ash + (j * 256 + w * 64) * 16;
            gl2lds16(A + (size_t)(m0 + r) * DIMsz + k0 + gc, lb);
            char* lb2 = (char*)Bsh + (j * 256 + w * 64) * 16;
            gl2lds16(B + (size_t)(n0 + r) * DIMsz + k0 + gc, lb2);
        }
        __syncthreads();

        #pragma unroll
        for (int ks2 = 0; ks2 < 2; ks2++) {
            f16x8 af[4], bf[4];
            #pragma unroll
            for (int mt = 0; mt < 4; mt++) {
                int ar = wm * 64 + mt * 16 + low;
                int c = ks2 * 4 + quad;
                af[mt] = *(const f16x8*)&Ash[ar * 64 + ((c ^ (ar & 7)) << 3)];
            }
            #pragma unroll
            for (int nt = 0; nt < 4; nt++) {
                int br = wn * 64 + nt * 16 + low;
                int c = ks2 * 4 + quad;
                bf[nt] = *(const f16x8*)&Bsh[br * 64 + ((c ^ (br & 7)) << 3)];
            }
            #pragma unroll
            for (int mt = 0; mt < 4; mt++)
                #pragma unroll
                for (int nt = 0; nt < 4; nt++)
                    acc[mt][nt] = __builtin_amdgcn_mfma_f32_16x16x32_f16(
                        af[mt], bf[nt], acc[mt][nt], 0, 0, 0);
        }
    }

    const int proj = n0 >> 9;                 // uniform per block
    if (proj < 2) {
        f16* dst = (proj == 0) ? qh : kh;
        #pragma unroll
        for (int nt = 0; nt < 4; nt++) {
            int n = n0 + wn * 64 + nt * 16 + low;
            int c = n & 511, h = c >> 6, d = c & 63;
            #pragma unroll
            for (int mt = 0; mt < 4; mt++)
                #pragma unroll
                for (int r = 0; r < 4; r++) {
                    int m = m0 + wm * 64 + mt * 16 + quad * 4 + r;
                    int b_ = m >> 11, l = m & (Lsz - 1);
                    size_t bh = (size_t)(b_ * Hsz + h);
                    dst[(bh * Lsz + l) * Dsz + d] = (f16)acc[mt][nt][r];
                }
        }
    } else {
        // v: transpose per head through LDS, then coalesced stores
        const int hb = (n0 & 511) >> 6;
        f16* Tv = (f16*)smem;                 // [64 d][136]
        const int b_ = m0 >> 11, l0 = m0 & (Lsz - 1);
        #pragma unroll 1
        for (int hs = 0; hs < 2; hs++) {
            __syncthreads();
            if (wn == hs) {
                #pragma unroll
                for (int nt = 0; nt < 4; nt++) {
                    int d = nt * 16 + low;
                    #pragma unroll
                    for (int mt = 0; mt < 4; mt++)
                        #pragma unroll
                        for (int r = 0; r < 4; r++) {
                            int l = wm * 64 + mt * 16 + quad * 4 + r;
                            Tv[d * 136 + l] = (f16)acc[mt][nt][r];
                        }
                }
            }
            __syncthreads();
            int d = tid >> 2, seg = tid & 3;
            size_t bh = (size_t)(b_ * Hsz + hb + hs);
            f16* dstp = vth + (bh * 64 + d) * (size_t)Lsz + l0 + seg * 32;
            const f16* srcp = Tv + d * 136 + seg * 32;
            #pragma unroll
            for (int j = 0; j < 4; j++)
                *(f16x8*)(dstp + j * 8) = *(const f16x8*)(srcp + j * 8);
        }
    }
}

// ---------------- MFMA flash attention (2-way key x 2-way q split) -----------
// grid (B*H=32 fastest -> XCD locality, L/64=32), block 256 = 4 waves.
// Round = 64 keys. Wave (kw = w&1, qw = w>>1): 32 keys (kw) x 32 q (qw).
// LDS 33KB: Kb0 [0,8K) Kb1 [8K,16K) Vb0 [16K,24K) Vb1 [24K,32K) Ls [32K,33K).
// Staging per round: 4 x gl2lds (K rows 0-31/32-63, V d-rows 0-31/32-63).
// 2-way split-K merge + per-qt parallel ctx write at the end.
__global__ __launch_bounds__(256, 3) void attn_mfma(
    const f16* __restrict__ q, const f16* __restrict__ k,
    const f16* __restrict__ vt, f16* __restrict__ ctx)
{
    __shared__ __align__(16) char smem[33792];

    const int tid = threadIdx.x;
    const int w = tid >> 6, lane = tid & 63;
    const int col = lane & 31;
    const int h = lane >> 5;
    const int kw = w & 1, qw = w >> 1;
    const int bh = blockIdx.x;        // fastest -> 4 heads per XCD
    const int qb = blockIdx.y;
    const int q0 = qb * 64;
    const size_t kvb = (size_t)bh * Lsz;

    f16* Ks = (f16*)smem;             // buf0 [64 key][64 d], 8-chunk XOR swz
    f16* Vs = (f16*)(smem + 16384);   // buf0 [64 d][64 key], 8-chunk XOR swz

    // Q B-frags for own q-tile: B[k=d][n=q], lane n=col, k = s*16 + h*8 + j
    f16x8 qf[4];
    #pragma unroll
    for (int s = 0; s < 4; s++)
        qf[s] = *(const f16x8*)(q + (kvb + q0 + qw * 32 + col) * Dsz
                                  + s * 16 + h * 8);
    // Retire q loads before manual vmcnt bookkeeping starts.
    #pragma unroll
    for (int s = 0; s < 4; s++)
        asm volatile("" :: "v"(qf[s]));

    // staging source base pointers (lane-specific, bumped per round)
    const f16* kp; const f16* vp;
    {
        int r8 = tid >> 3, g8 = tid & 7;          // rows 0..31 per call
        kp = k + (kvb + r8) * Dsz + ((g8 ^ (r8 & 7)) << 3);
        vp = vt + ((size_t)bh * Dsz + r8) * Lsz + ((g8 ^ (r8 & 7)) << 3);
    }
    char* kl = (char*)smem + w * 1024;            // wave-uniform LDS dests
    char* vl = (char*)smem + 16384 + w * 1024;    // + parity*8192 at call

    // loop-invariant LDS frag pointers (buf0; +8192 selects buf1)
    const f16* kfp[4];
    #pragma unroll
    for (int s = 0; s < 4; s++)
        kfp[s] = Ks + (kw * 32 + col) * 64 + (((s * 2 + h) ^ (col & 7)) << 3);
    const f16* vfp[2][2];
    #pragma unroll
    for (int dt = 0; dt < 2; dt++)
        #pragma unroll
        for (int ks = 0; ks < 2; ks++) {
            int cv = kw * 4 + ks * 2 + h;
            vfp[dt][ks] = Vs + (dt * 32 + col) * 64 + ((cv ^ (col & 7)) << 3);
        }

    f32x16 acc[2];                    // O^T partial [dt], cols = own 32 q
    #pragma unroll
    for (int dt = 0; dt < 2; dt++)
        #pragma unroll
        for (int i = 0; i < 16; i++) acc[dt][i] = 0.f;
    float lsum = 0.f;

    // prologue: stage round 0 into buf0
    gl2lds16(kp,            kl);
    gl2lds16(kp + 32 * Dsz, kl + 4096);
    gl2lds16(vp,            vl);
    gl2lds16(vp + 32 * Lsz, vl + 4096);
    kp += 64 * Dsz;
    vp += 64;

#define ATTN_ROUND(S0, P, PRE) do {                                           \
    const int ko_ = (P) * 8192;                                               \
    if (PRE) {                                                                \
        const int nx_ = ((P) ^ 1) * 8192;                                     \
        gl2lds16(kp,            kl + nx_);                                    \
        gl2lds16(kp + 32 * Dsz, kl + nx_ + 4096);                             \
        gl2lds16(vp,            vl + nx_);                                    \
        gl2lds16(vp + 32 * Lsz, vl + nx_ + 4096);                             \
        kp += 64 * Dsz;                                                       \
        vp += 64;                                                             \
        asm volatile("s_waitcnt vmcnt(4)" ::: "memory");                      \
    } else {                                                                  \
        asm volatile("s_waitcnt vmcnt(0)" ::: "memory");                      \
    }                                                                         \
    __builtin_amdgcn_s_barrier();                                             \
    __builtin_amdgcn_sched_barrier(0);                                        \
    /* ---- S^T: A = own 32 K rows, B = own q-tile; 4 k-steps over d ---- */  \
    f32x16 st;                                                                \
    _Pragma("unroll")                                                         \
    for (int i = 0; i < 16; i++) st[i] = 0.f;                                 \
    __builtin_amdgcn_s_setprio(1);                                            \
    _Pragma("unroll")                                                         \
    for (int s = 0; s < 4; s++) {                                             \
        f16x8 kf = *(const f16x8*)((const char*)kfp[s] + ko_);                \
        st = __builtin_amdgcn_mfma_f32_32x32x16_f16(kf, qf[s], st, 0, 0, 0);  \
    }                                                                         \
    __builtin_amdgcn_s_setprio(0);                                            \
    /* ---- softmax numerators (in-place exp2) + diag mask ---- */            \
    _Pragma("unroll")                                                         \
    for (int i = 0; i < 16; i++) st[i] = EXP2(st[i]);                         \
    if ((S0) == q0 && kw == qw) {                                             \
        _Pragma("unroll")                                                     \
        for (int i = 0; i < 16; i++) {                                        \
            int row = (i & 3) + 8 * (i >> 2) + 4 * h;                         \
            st[i] = (row == col) ? 0.f : st[i];                               \
        }                                                                     \
    }                                                                         \
    _Pragma("unroll")                                                         \
    for (int i = 0; i < 16; i++) lsum += st[i];                               \
    /* ---- C->B transform ---- */                                            \
    u32 P2[8];                                                                \
    _Pragma("unroll")                                                         \
    for (int j = 0; j < 8; j++)                                               \
        P2[j] = pack2(st[2 * j], st[2 * j + 1]);                              \
    plswap(P2[0], P2[2]); plswap(P2[1], P2[3]);                               \
    plswap(P2[4], P2[6]); plswap(P2[5], P2[7]);                               \
    union { u32 u[4]; f16x8 v; } pfa, pfb;                                    \
    _Pragma("unroll")                                                         \
    for (int jj = 0; jj < 4; jj++) {                                          \
        pfa.u[jj] = P2[jj];                                                   \
        pfb.u[jj] = P2[4 + jj];                                               \
    }                                                                         \
    /* ---- O^T += V^T . P over own 32 keys ---- */                           \
    __builtin_amdgcn_s_setprio(1);                                            \
    _Pragma("unroll")                                                         \
    for (int dt = 0; dt < 2; dt++) {                                          \
        f16x8 vf0 = *(const f16x8*)((const char*)vfp[dt][0] + ko_);           \
        acc[dt] = __builtin_amdgcn_mfma_f32_32x32x16_f16(                     \
            vf0, pfa.v, acc[dt], 0, 0, 0);                                    \
        f16x8 vf1 = *(const f16x8*)((const char*)vfp[dt][1] + ko_);           \
        acc[dt] = __builtin_amdgcn_mfma_f32_32x32x16_f16(                     \
            vf1, pfb.v, acc[dt], 0, 0, 0);                                    \
    }                                                                         \
    __builtin_amdgcn_s_setprio(0);                                            \
    __builtin_amdgcn_sched_barrier(0);                                        \
    __builtin_amdgcn_s_barrier();                                             \
} while (0)

    #pragma unroll 1
    for (int s0 = 0; s0 < Lsz; s0 += 128) {
        ATTN_ROUND(s0, 0, true);
        ATTN_ROUND(s0 + 64, 1, (s0 + 128 < Lsz));
    }
#undef ATTN_ROUND

    // all waves out of the loop before LDS scratch reuse
    __syncthreads();

    // lsum: reduce over half-wave, publish per-wave partial (extra 1KB).
    float* Lsp = (float*)(smem + 32768);
    lsum += __shfl_xor(lsum, 32);
    if (h == 0) Lsp[qw * 64 + kw * 32 + col] = lsum;

    // ---- 2-way split-K merge via reused K-dbuf LDS (2 x 8KB slots) ----
    float* Om = (float*)smem;                     // [qw][64 d][32 q] f32
    if (kw == 1) {
        float* og = Om + qw * 2048;
        #pragma unroll
        for (int dt = 0; dt < 2; dt++)
            #pragma unroll
            for (int i = 0; i < 16; i++) {
                int row = (i & 3) + 8 * (i >> 2) + 4 * h;
                og[(dt * 32 + row) * 32 + col] = acc[dt][i];
            }
    }
    __syncthreads();
    if (kw == 0) {
        const float* og = Om + qw * 2048;
        #pragma unroll
        for (int dt = 0; dt < 2; dt++)
            #pragma unroll
            for (int i = 0; i < 16; i++) {
                int row = (i & 3) + 8 * (i >> 2) + 4 * h;
                acc[dt][i] += og[(dt * 32 + row) * 32 + col];
            }
        const int b = bh >> 3, hh = bh & 7;
        float ls = Lsp[qw * 64 + col] + Lsp[qw * 64 + 32 + col];
        const float inv = 1.0f / ls;
        f16* op = ctx + ((size_t)(b * Lsz + q0 + qw * 32 + col)) * DIMsz
                      + hh * 64;
        #pragma unroll
        for (int dt = 0; dt < 2; dt++)
            #pragma unroll
            for (int r4 = 0; r4 < 4; r4++) {
                f16x4 o;
                o.x = (f16)(acc[dt][4 * r4 + 0] * inv);
                o.y = (f16)(acc[dt][4 * r4 + 1] * inv);
                o.z = (f16)(acc[dt][4 * r4 + 2] * inv);
                o.w = (f16)(acc[dt][4 * r4 + 3] * inv);
                *(f16x4*)(op + dt * 32 + 8 * r4 + 4 * h) = o;
            }
    }
}

// ---------------- out-proj MFMA GEMM: out(fp32) = ctx @ wo^T -----------------
__global__ __launch_bounds__(256) void gemm_out_f16(
    const f16* __restrict__ A, const f16* __restrict__ B,
    float* __restrict__ C)
{
    __shared__ f16 Ash[64 * 64];
    __shared__ f16 Bsh[64 * 64];
    const int tid = threadIdx.x;
    const int w = tid >> 6, lane = tid & 63;
    const int quad = lane >> 4, low = lane & 15;
    const int wm = w >> 1, wn = w & 1;
    const int m0 = blockIdx.y * 64, n0 = blockIdx.x * 64;

    f32x4 acc[2][2];
    #pragma unroll
    for (int i = 0; i < 2; i++)
        #pragma unroll
        for (int j = 0; j < 2; j++) acc[i][j] = (f32x4){0.f, 0.f, 0.f, 0.f};

    #pragma unroll 1
    for (int k0 = 0; k0 < DIMsz; k0 += 64) {
        __syncthreads();
        #pragma unroll
        for (int j = 0; j < 2; j++) {
            int t = j * 256 + tid;
            int r = t >> 3, g = t & 7;                 // 64 rows x 8 chunks
            int gc = (g ^ (r & 7)) * 8;
            char* lb = (char*)Ash + (j * 256 + w * 64) * 16;
            gl2lds16(A + (size_t)(m0 + r) * DIMsz + k0 + gc, lb);
            char* lb2 = (char*)Bsh + (j * 256 + w * 64) * 16;
            gl2lds16(B + (size_t)(n0 + r) * DIMsz + k0 + gc, lb2);
        }
        __syncthreads();

        #pragma unroll
        for (int ks2 = 0; ks2 < 2; ks2++) {
            f16x8 af[2], bf[2];
            #pragma unroll
            for (int mt = 0; mt < 2; mt++) {
                int ar = wm * 32 + mt * 16 + low;
                int c = ks2 * 4 + quad;
                af[mt] = *(const f16x8*)&Ash[ar * 64 + ((c ^ (ar & 7)) << 3)];
            }
            #pragma unroll
            for (int nt = 0; nt < 2; nt++) {
                int br = wn * 32 + nt * 16 + low;
                int c = ks2 * 4 + quad;
                bf[nt] = *(const f16x8*)&Bsh[br * 64 + ((c ^ (br & 7)) << 3)];
            }
            #pragma unroll
            for (int mt = 0; mt < 2; mt++)
                #pragma unroll
                for (int nt = 0; nt < 2; nt++)
                    acc[mt][nt] = __builtin_amdgcn_mfma_f32_16x16x32_f16(
                        af[mt], bf[nt], acc[mt][nt], 0, 0, 0);
        }
    }

    #pragma unroll
    for (int mt = 0; mt < 2; mt++)
        #pragma unroll
        for (int r = 0; r < 4; r++) {
            int m = m0 + wm * 32 + mt * 16 + quad * 4 + r;
            #pragma unroll
            for (int nt = 0; nt < 2; nt++) {
                int n = n0 + wn * 32 + nt * 16 + low;
                C[(size_t)m * DIMsz + n] = acc[mt][nt][r];
            }
        }
}

extern "C" void kernel_launch(void* const* d_in, const int* in_sizes, int n_in,
                              void* d_out, int out_size, void* d_ws, size_t ws_size,
                              hipStream_t stream) {
    const float* x  = (const float*)d_in[0];
    const float* wq = (const float*)d_in[1];
    const float* wk = (const float*)d_in[2];
    const float* wv = (const float*)d_in[3];
    const float* wo = (const float*)d_in[4];
    float* out = (float*)d_out;

    const size_t NTOK = (size_t)Bsz * Lsz;   // 8192
    const size_t XSZ  = NTOK * DIMsz;        // 4,194,304

    f16* xh   = (f16*)d_ws;                  // 8 MB
    f16* w3h  = xh + XSZ;                    // 1.5 MB  [1536][512]
    f16* woh  = w3h + 3 * 262144;            // 0.5 MB
    f16* qh   = woh + 262144;                // 8 MB [bh][l][d] (scale*log2e)
    f16* kh   = qh + XSZ;                    // 8 MB [bh][l][d]
    f16* vth  = kh + XSZ;                    // 8 MB [bh][d][l]
    f16* ctxh = vth + XSZ;                   // 8 MB [b*l][512]

    pack_f16<<<5120, 256, 0, stream>>>(x, wq, wk, wv, wo, xh, w3h, woh);

    dim3 g1(1536 / 128, NTOK / 128);         // (12, 64)
    gemm_qkv_f16<<<g1, 256, 0, stream>>>(xh, w3h, qh, kh, vth);

    dim3 g2(Bsz * Hsz, Lsz / 64);            // (32 bh, 32 qb) — bh fastest
    attn_mfma<<<g2, 256, 0, stream>>>(qh, kh, vth, ctxh);

    dim3 g3(DIMsz / 64, NTOK / 64);          // (8, 128)
    gemm_out_f16<<<g3, 256, 0, stream>>>(ctxh, woh, out);
}

// Round 9
// 158.240 us; speedup vs baseline: 1.4429x; 1.0269x over previous
//
#include <hip/hip_runtime.h>
#include <hip/hip_bf16.h>

// B=4, L=2048, DIM=512, H=8, D=64, fp32 in/out.
// pack fp32->fp16 (log2e folded into wq) -> fused QKV MFMA GEMM (BK=64, V^T
// via in-LDS transpose epilogue) -> 32x32x16-MFMA flash attn (64-key rounds,
// 4 waves = 2-way key split x 2-way q split, 32 keys x 32 q per wave,
// K+V DOUBLE-BUFFERED gl2lds with counted vmcnt + 2 raw barriers/round
// [T3/T4, 33.8KB LDS -> 4 blocks/CU], extended XOR swizzle (row&7 ^ row>>3)
// to cut 4-way frag-read bank conflicts, setprio [T5], permlane32_swap
// P-transform) -> out-proj MFMA GEMM (64^2).
// NOTE: global_load_lds imm offset applies to the GLOBAL address only; the
// LDS dest is always M0 + lane*16 -> multi-call staging must bump BOTH ptrs.
// NOTE: main loop uses raw s_barrier + asm s_waitcnt vmcnt(4): the 4
// prefetch loads for round r+1 stay in flight across the barrier.
// LESSON (R3-R6): mid-round staging / 3-barrier variants spill (~30MB
// anomalous HBM writes, 2x slower). Keep the 2-barrier schedule exactly.
// SWIZZLE: LDS slot (row, j) holds global chunk j ^ (row&7) ^ ((row>>3)&3).
// Staging source and frag reads use the same involution; staging stays a
// single base pointer because rows +32 leave (r>>3)&3 unchanged, and read
// rows kw*32+col / dt*32+col reduce to (col>>3)&3.

#define Bsz 4
#define Lsz 2048
#define DIMsz 512
#define Hsz 8
#define Dsz 64

typedef _Float16 f16;
typedef __attribute__((ext_vector_type(8))) _Float16 f16x8;
typedef __attribute__((ext_vector_type(4))) _Float16 f16x4;
typedef __attribute__((ext_vector_type(2))) __fp16 fp16x2;  // builtin ret type
typedef __attribute__((ext_vector_type(4))) float f32x4;
typedef __attribute__((ext_vector_type(16))) float f32x16;
typedef unsigned int u32;
typedef __attribute__((ext_vector_type(2))) unsigned int u32x2;

#if __has_builtin(__builtin_amdgcn_exp2f)
#define EXP2(x) __builtin_amdgcn_exp2f(x)
#else
#define EXP2(x) __expf(0.6931471805599453f * (x))
#endif

__device__ __forceinline__ u32 pack2(float a, float b) {
#if __has_builtin(__builtin_amdgcn_cvt_pkrtz)
    fp16x2 h = __builtin_amdgcn_cvt_pkrtz(a, b);
    return __builtin_bit_cast(u32, h);
#else
    fp16x2 h; h.x = (__fp16)a; h.y = (__fp16)b;
    return __builtin_bit_cast(u32, h);
#endif
}

// Cross-half exchange for the 32x32 C->B P-transform.
#if __has_builtin(__builtin_amdgcn_permlane32_swap)
__device__ __forceinline__ void plswap(u32& a, u32& b) {
    u32x2 r = __builtin_amdgcn_permlane32_swap(a, b, false, false);
    a = r.x; b = r.y;
}
#else
__device__ __forceinline__ void plswap(u32& a, u32& b) {
    u32 sa = (u32)__shfl_xor((int)a, 32);
    u32 sb = (u32)__shfl_xor((int)b, 32);
    bool hi = (threadIdx.x & 32) != 0;
    u32 na = hi ? sb : a;
    u32 nb = hi ? b : sa;
    a = na; b = nb;
}
#endif

__device__ __forceinline__ void gl2lds16(const void* g, void* l) {
    __builtin_amdgcn_global_load_lds(
        (const __attribute__((address_space(1))) u32*)g,
        (__attribute__((address_space(3))) u32*)l, 16, 0, 0);
}

// ---------------- pack: fp32 -> fp16 ----------------------------------------
__global__ __launch_bounds__(256) void pack_f16(
    const float* __restrict__ x, const float* __restrict__ wq,
    const float* __restrict__ wk, const float* __restrict__ wv,
    const float* __restrict__ wo,
    f16* __restrict__ xh, f16* __restrict__ w3h, f16* __restrict__ woh)
{
    int bx = blockIdx.x, seg, blk;
    if (bx < 4096) { seg = 0; blk = bx; }
    else { seg = 1 + ((bx - 4096) >> 8); blk = (bx - 4096) & 255; }
    const float* s; f16* d; float sc = 1.0f;
    switch (seg) {
        case 0: s = x;  d = xh;            break;
        case 1: s = wq; d = w3h;           sc = 0.18033688011112042f; break;
        case 2: s = wk; d = w3h + 262144;  break;
        case 3: s = wv; d = w3h + 524288;  break;
        default: s = wo; d = woh;          break;
    }
    int i = (blk * 256 + threadIdx.x) * 4;
    float4 v = *(const float4*)(s + i);
    f16x4 o;
    o.x = (f16)(v.x * sc); o.y = (f16)(v.y * sc);
    o.z = (f16)(v.z * sc); o.w = (f16)(v.w * sc);
    *(f16x4*)(d + i) = o;
}

// ---------------- fused QKV MFMA GEMM (BK=64) --------------------------------
__global__ __launch_bounds__(256) void gemm_qkv_f16(
    const f16* __restrict__ A, const f16* __restrict__ B,
    f16* __restrict__ qh, f16* __restrict__ kh, f16* __restrict__ vth)
{
    __shared__ __align__(16) char smem[32768];   // A 16K | B 16K ; Tv reuse
    f16* Ash = (f16*)smem;
    f16* Bsh = (f16*)(smem + 16384);

    const int tid = threadIdx.x;
    const int w = tid >> 6, lane = tid & 63;
    const int quad = lane >> 4, low = lane & 15;
    const int wm = w >> 1, wn = w & 1;
    const int m0 = blockIdx.y * 128, n0 = blockIdx.x * 128;

    f32x4 acc[4][4];
    #pragma unroll
    for (int i = 0; i < 4; i++)
        #pragma unroll
        for (int j = 0; j < 4; j++) acc[i][j] = (f32x4){0.f, 0.f, 0.f, 0.f};

    #pragma unroll 1
    for (int k0 = 0; k0 < DIMsz; k0 += 64) {
        __syncthreads();
        #pragma unroll
        for (int j = 0; j < 4; j++) {
            int t = j * 256 + tid;
            int r = t >> 3, g = t & 7;                 // 128 rows x 8 chunks
            int gc = (g ^ (r & 7)) * 8;
            char* lb = (char*)Ash + (j * 256 + w * 64) * 16;
            gl2lds16(A + (size_t)(m0 + r) * DIMsz + k0 + gc, lb);
            char* lb2 = (char*)Bsh + (j * 256 + w * 64) * 16;
            gl2lds16(B + (size_t)(n0 + r) * DIMsz + k0 + gc, lb2);
        }
        __syncthreads();

        #pragma unroll
        for (int ks2 = 0; ks2 < 2; ks2++) {
            f16x8 af[4], bf[4];
            #pragma unroll
            for (int mt = 0; mt < 4; mt++) {
                int ar = wm * 64 + mt * 16 + low;
                int c = ks2 * 4 + quad;
                af[mt] = *(const f16x8*)&Ash[ar * 64 + ((c ^ (ar & 7)) << 3)];
            }
            #pragma unroll
            for (int nt = 0; nt < 4; nt++) {
                int br = wn * 64 + nt * 16 + low;
                int c = ks2 * 4 + quad;
                bf[nt] = *(const f16x8*)&Bsh[br * 64 + ((c ^ (br & 7)) << 3)];
            }
            #pragma unroll
            for (int mt = 0; mt < 4; mt++)
                #pragma unroll
                for (int nt = 0; nt < 4; nt++)
                    acc[mt][nt] = __builtin_amdgcn_mfma_f32_16x16x32_f16(
                        af[mt], bf[nt], acc[mt][nt], 0, 0, 0);
        }
    }

    const int proj = n0 >> 9;                 // uniform per block
    if (proj < 2) {
        f16* dst = (proj == 0) ? qh : kh;
        #pragma unroll
        for (int nt = 0; nt < 4; nt++) {
            int n = n0 + wn * 64 + nt * 16 + low;
            int c = n & 511, h = c >> 6, d = c & 63;
            #pragma unroll
            for (int mt = 0; mt < 4; mt++)
                #pragma unroll
                for (int r = 0; r < 4; r++) {
                    int m = m0 + wm * 64 + mt * 16 + quad * 4 + r;
                    int b_ = m >> 11, l = m & (Lsz - 1);
                    size_t bh = (size_t)(b_ * Hsz + h);
                    dst[(bh * Lsz + l) * Dsz + d] = (f16)acc[mt][nt][r];
                }
        }
    } else {
        // v: transpose per head through LDS, then coalesced stores
        const int hb = (n0 & 511) >> 6;
        f16* Tv = (f16*)smem;                 // [64 d][136]
        const int b_ = m0 >> 11, l0 = m0 & (Lsz - 1);
        #pragma unroll 1
        for (int hs = 0; hs < 2; hs++) {
            __syncthreads();
            if (wn == hs) {
                #pragma unroll
                for (int nt = 0; nt < 4; nt++) {
                    int d = nt * 16 + low;
                    #pragma unroll
                    for (int mt = 0; mt < 4; mt++)
                        #pragma unroll
                        for (int r = 0; r < 4; r++) {
                            int l = wm * 64 + mt * 16 + quad * 4 + r;
                            Tv[d * 136 + l] = (f16)acc[mt][nt][r];
                        }
                }
            }
            __syncthreads();
            int d = tid >> 2, seg = tid & 3;
            size_t bh = (size_t)(b_ * Hsz + hb + hs);
            f16* dstp = vth + (bh * 64 + d) * (size_t)Lsz + l0 + seg * 32;
            const f16* srcp = Tv + d * 136 + seg * 32;
            #pragma unroll
            for (int j = 0; j < 4; j++)
                *(f16x8*)(dstp + j * 8) = *(const f16x8*)(srcp + j * 8);
        }
    }
}

// ---------------- MFMA flash attention (2-way key x 2-way q split) -----------
// grid (B*H=32 fastest -> XCD locality, L/64=32), block 256 = 4 waves.
// Round = 64 keys. Wave (kw = w&1, qw = w>>1): 32 keys (kw) x 32 q (qw).
// LDS 33KB: Kb0 [0,8K) Kb1 [8K,16K) Vb0 [16K,24K) Vb1 [24K,32K) Ls [32K,33K).
// Staging per round: 4 x gl2lds (K rows 0-31/32-63, V d-rows 0-31/32-63).
// 2-way split-K merge + per-qt parallel ctx write at the end.
__global__ __launch_bounds__(256, 4) void attn_mfma(
    const f16* __restrict__ q, const f16* __restrict__ k,
    const f16* __restrict__ vt, f16* __restrict__ ctx)
{
    __shared__ __align__(16) char smem[33792];

    const int tid = threadIdx.x;
    const int w = tid >> 6, lane = tid & 63;
    const int col = lane & 31;
    const int h = lane >> 5;
    const int kw = w & 1, qw = w >> 1;
    const int bh = blockIdx.x;        // fastest -> 4 heads per XCD
    const int qb = blockIdx.y;
    const int q0 = qb * 64;
    const size_t kvb = (size_t)bh * Lsz;

    f16* Ks = (f16*)smem;             // buf0 [64 key][64 d], ext-XOR swizzle
    f16* Vs = (f16*)(smem + 16384);   // buf0 [64 d][64 key], ext-XOR swizzle

    // Q B-frags for own q-tile: B[k=d][n=q], lane n=col, k = s*16 + h*8 + j
    f16x8 qf[4];
    #pragma unroll
    for (int s = 0; s < 4; s++)
        qf[s] = *(const f16x8*)(q + (kvb + q0 + qw * 32 + col) * Dsz
                                  + s * 16 + h * 8);
    // Retire q loads before manual vmcnt bookkeeping starts.
    #pragma unroll
    for (int s = 0; s < 4; s++)
        asm volatile("" :: "v"(qf[s]));

    // staging source base pointers (lane-specific, bumped per round).
    // chunk perm: slot (r, g) holds global chunk g ^ (r&7) ^ ((r>>3)&3);
    // rows +32 leave (r>>3)&3 unchanged -> one base ptr serves both calls.
    const f16* kp; const f16* vp;
    {
        int r8 = tid >> 3, g8 = tid & 7;          // rows 0..31 per call
        int gc = (g8 ^ (r8 & 7) ^ ((r8 >> 3) & 3)) << 3;
        kp = k + (kvb + r8) * Dsz + gc;
        vp = vt + ((size_t)bh * Dsz + r8) * Lsz + gc;
    }
    char* kl = (char*)smem + w * 1024;            // wave-uniform LDS dests
    char* vl = (char*)smem + 16384 + w * 1024;    // + parity*8192 at call

    // loop-invariant LDS frag pointers (buf0; +8192 selects buf1).
    // read row kw*32+col / dt*32+col -> (row>>3)&3 == (col>>3)&3.
    const int cswz = (col & 7) ^ ((col >> 3) & 3);
    const f16* kfp[4];
    #pragma unroll
    for (int s = 0; s < 4; s++)
        kfp[s] = Ks + (kw * 32 + col) * 64 + (((s * 2 + h) ^ cswz) << 3);
    const f16* vfp[2][2];
    #pragma unroll
    for (int dt = 0; dt < 2; dt++)
        #pragma unroll
        for (int ks = 0; ks < 2; ks++) {
            int cv = kw * 4 + ks * 2 + h;
            vfp[dt][ks] = Vs + (dt * 32 + col) * 64 + ((cv ^ cswz) << 3);
        }

    f32x16 acc[2];                    // O^T partial [dt], cols = own 32 q
    #pragma unroll
    for (int dt = 0; dt < 2; dt++)
        #pragma unroll
        for (int i = 0; i < 16; i++) acc[dt][i] = 0.f;
    float lsum = 0.f;

    // prologue: stage round 0 into buf0
    gl2lds16(kp,            kl);
    gl2lds16(kp + 32 * Dsz, kl + 4096);
    gl2lds16(vp,            vl);
    gl2lds16(vp + 32 * Lsz, vl + 4096);
    kp += 64 * Dsz;
    vp += 64;

#define ATTN_ROUND(S0, P, PRE) do {                                           \
    const int ko_ = (P) * 8192;                                               \
    if (PRE) {                                                                \
        const int nx_ = ((P) ^ 1) * 8192;                                     \
        gl2lds16(kp,            kl + nx_);                                    \
        gl2lds16(kp + 32 * Dsz, kl + nx_ + 4096);                             \
        gl2lds16(vp,            vl + nx_);                                    \
        gl2lds16(vp + 32 * Lsz, vl + nx_ + 4096);                             \
        kp += 64 * Dsz;                                                       \
        vp += 64;                                                             \
        asm volatile("s_waitcnt vmcnt(4)" ::: "memory");                      \
    } else {                                                                  \
        asm volatile("s_waitcnt vmcnt(0)" ::: "memory");                      \
    }                                                                         \
    __builtin_amdgcn_s_barrier();                                             \
    __builtin_amdgcn_sched_barrier(0);                                        \
    /* ---- S^T: A = own 32 K rows, B = own q-tile; 4 k-steps over d ---- */  \
    f32x16 st;                                                                \
    _Pragma("unroll")                                                         \
    for (int i = 0; i < 16; i++) st[i] = 0.f;                                 \
    __builtin_amdgcn_s_setprio(1);                                            \
    _Pragma("unroll")                                                         \
    for (int s = 0; s < 4; s++) {                                             \
        f16x8 kf = *(const f16x8*)((const char*)kfp[s] + ko_);                \
        st = __builtin_amdgcn_mfma_f32_32x32x16_f16(kf, qf[s], st, 0, 0, 0);  \
    }                                                                         \
    __builtin_amdgcn_s_setprio(0);                                            \
    /* ---- softmax numerators (in-place exp2) + diag mask ---- */            \
    _Pragma("unroll")                                                         \
    for (int i = 0; i < 16; i++) st[i] = EXP2(st[i]);                         \
    if ((S0) == q0 && kw == qw) {                                             \
        _Pragma("unroll")                                                     \
        for (int i = 0; i < 16; i++) {                                        \
            int row = (i & 3) + 8 * (i >> 2) + 4 * h;                         \
            st[i] = (row == col) ? 0.f : st[i];                               \
        }                                                                     \
    }                                                                         \
    _Pragma("unroll")                                                         \
    for (int i = 0; i < 16; i++) lsum += st[i];                               \
    /* ---- C->B transform ---- */                                            \
    u32 P2[8];                                                                \
    _Pragma("unroll")                                                         \
    for (int j = 0; j < 8; j++)                                               \
        P2[j] = pack2(st[2 * j], st[2 * j + 1]);                              \
    plswap(P2[0], P2[2]); plswap(P2[1], P2[3]);                               \
    plswap(P2[4], P2[6]); plswap(P2[5], P2[7]);                               \
    union { u32 u[4]; f16x8 v; } pfa, pfb;                                    \
    _Pragma("unroll")                                                         \
    for (int jj = 0; jj < 4; jj++) {                                          \
        pfa.u[jj] = P2[jj];                                                   \
        pfb.u[jj] = P2[4 + jj];                                               \
    }                                                                         \
    /* ---- O^T += V^T . P over own 32 keys ---- */                           \
    __builtin_amdgcn_s_setprio(1);                                            \
    _Pragma("unroll")                                                         \
    for (int dt = 0; dt < 2; dt++) {                                          \
        f16x8 vf0 = *(const f16x8*)((const char*)vfp[dt][0] + ko_);           \
        acc[dt] = __builtin_amdgcn_mfma_f32_32x32x16_f16(                     \
            vf0, pfa.v, acc[dt], 0, 0, 0);                                    \
        f16x8 vf1 = *(const f16x8*)((const char*)vfp[dt][1] + ko_);           \
        acc[dt] = __builtin_amdgcn_mfma_f32_32x32x16_f16(                     \
            vf1, pfb.v, acc[dt], 0, 0, 0);                                    \
    }                                                                         \
    __builtin_amdgcn_s_setprio(0);                                            \
    __builtin_amdgcn_sched_barrier(0);                                        \
    __builtin_amdgcn_s_barrier();                                             \
} while (0)

    #pragma unroll 1
    for (int s0 = 0; s0 < Lsz; s0 += 128) {
        ATTN_ROUND(s0, 0, true);
        ATTN_ROUND(s0 + 64, 1, (s0 + 128 < Lsz));
    }
#undef ATTN_ROUND

    // all waves out of the loop before LDS scratch reuse
    __syncthreads();

    // lsum: reduce over half-wave, publish per-wave partial (extra 1KB).
    float* Lsp = (float*)(smem + 32768);
    lsum += __shfl_xor(lsum, 32);
    if (h == 0) Lsp[qw * 64 + kw * 32 + col] = lsum;

    // ---- 2-way split-K merge via reused K-dbuf LDS (2 x 8KB slots) ----
    float* Om = (float*)smem;                     // [qw][64 d][32 q] f32
    if (kw == 1) {
        float* og = Om + qw * 2048;
        #pragma unroll
        for (int dt = 0; dt < 2; dt++)
            #pragma unroll
            for (int i = 0; i < 16; i++) {
                int row = (i & 3) + 8 * (i >> 2) + 4 * h;
                og[(dt * 32 + row) * 32 + col] = acc[dt][i];
            }
    }
    __syncthreads();
    if (kw == 0) {
        const float* og = Om + qw * 2048;
        #pragma unroll
        for (int dt = 0; dt < 2; dt++)
            #pragma unroll
            for (int i = 0; i < 16; i++) {
                int row = (i & 3) + 8 * (i >> 2) + 4 * h;
                acc[dt][i] += og[(dt * 32 + row) * 32 + col];
            }
        const int b = bh >> 3, hh = bh & 7;
        float ls = Lsp[qw * 64 + col] + Lsp[qw * 64 + 32 + col];
        const float inv = 1.0f / ls;
        f16* op = ctx + ((size_t)(b * Lsz + q0 + qw * 32 + col)) * DIMsz
                      + hh * 64;
        #pragma unroll
        for (int dt = 0; dt < 2; dt++)
            #pragma unroll
            for (int r4 = 0; r4 < 4; r4++) {
                f16x4 o;
                o.x = (f16)(acc[dt][4 * r4 + 0] * inv);
                o.y = (f16)(acc[dt][4 * r4 + 1] * inv);
                o.z = (f16)(acc[dt][4 * r4 + 2] * inv);
                o.w = (f16)(acc[dt][4 * r4 + 3] * inv);
                *(f16x4*)(op + dt * 32 + 8 * r4 + 4 * h) = o;
            }
    }
}

// ---------------- out-proj MFMA GEMM: out(fp32) = ctx @ wo^T -----------------
__global__ __launch_bounds__(256) void gemm_out_f16(
    const f16* __restrict__ A, const f16* __restrict__ B,
    float* __restrict__ C)
{
    __shared__ f16 Ash[64 * 64];
    __shared__ f16 Bsh[64 * 64];
    const int tid = threadIdx.x;
    const int w = tid >> 6, lane = tid & 63;
    const int quad = lane >> 4, low = lane & 15;
    const int wm = w >> 1, wn = w & 1;
    const int m0 = blockIdx.y * 64, n0 = blockIdx.x * 64;

    f32x4 acc[2][2];
    #pragma unroll
    for (int i = 0; i < 2; i++)
        #pragma unroll
        for (int j = 0; j < 2; j++) acc[i][j] = (f32x4){0.f, 0.f, 0.f, 0.f};

    #pragma unroll 1
    for (int k0 = 0; k0 < DIMsz; k0 += 64) {
        __syncthreads();
        #pragma unroll
        for (int j = 0; j < 2; j++) {
            int t = j * 256 + tid;
            int r = t >> 3, g = t & 7;                 // 64 rows x 8 chunks
            int gc = (g ^ (r & 7)) * 8;
            char* lb = (char*)Ash + (j * 256 + w * 64) * 16;
            gl2lds16(A + (size_t)(m0 + r) * DIMsz + k0 + gc, lb);
            char* lb2 = (char*)Bsh + (j * 256 + w * 64) * 16;
            gl2lds16(B + (size_t)(n0 + r) * DIMsz + k0 + gc, lb2);
        }
        __syncthreads();

        #pragma unroll
        for (int ks2 = 0; ks2 < 2; ks2++) {
            f16x8 af[2], bf[2];
            #pragma unroll
            for (int mt = 0; mt < 2; mt++) {
                int ar = wm * 32 + mt * 16 + low;
                int c = ks2 * 4 + quad;
                af[mt] = *(const f16x8*)&Ash[ar * 64 + ((c ^ (ar & 7)) << 3)];
            }
            #pragma unroll
            for (int nt = 0; nt < 2; nt++) {
                int br = wn * 32 + nt * 16 + low;
                int c = ks2 * 4 + quad;
                bf[nt] = *(const f16x8*)&Bsh[br * 64 + ((c ^ (br & 7)) << 3)];
            }
            #pragma unroll
            for (int mt = 0; mt < 2; mt++)
                #pragma unroll
                for (int nt = 0; nt < 2; nt++)
                    acc[mt][nt] = __builtin_amdgcn_mfma_f32_16x16x32_f16(
                        af[mt], bf[nt], acc[mt][nt], 0, 0, 0);
        }
    }

    #pragma unroll
    for (int mt = 0; mt < 2; mt++)
        #pragma unroll
        for (int r = 0; r < 4; r++) {
            int m = m0 + wm * 32 + mt * 16 + quad * 4 + r;
            #pragma unroll
            for (int nt = 0; nt < 2; nt++) {
                int n = n0 + wn * 32 + nt * 16 + low;
                C[(size_t)m * DIMsz + n] = acc[mt][nt][r];
            }
        }
}

extern "C" void kernel_launch(void* const* d_in, const int* in_sizes, int n_in,
                              void* d_out, int out_size, void* d_ws, size_t ws_size,
                              hipStream_t stream) {
    const float* x  = (const float*)d_in[0];
    const float* wq = (const float*)d_in[1];
    const float* wk = (const float*)d_in[2];
    const float* wv = (const float*)d_in[3];
    const float* wo = (const float*)d_in[4];
    float* out = (float*)d_out;

    const size_t NTOK = (size_t)Bsz * Lsz;   // 8192
    const size_t XSZ  = NTOK * DIMsz;        // 4,194,304

    f16* xh   = (f16*)d_ws;                  // 8 MB
    f16* w3h  = xh + XSZ;                    // 1.5 MB  [1536][512]
    f16* woh  = w3h + 3 * 262144;            // 0.5 MB
    f16* qh   = woh + 262144;                // 8 MB [bh][l][d] (scale*log2e)
    f16* kh   = qh + XSZ;                    // 8 MB [bh][l][d]
    f16* vth  = kh + XSZ;                    // 8 MB [bh][d][l]
    f16* ctxh = vth + XSZ;                   // 8 MB [b*l][512]

    pack_f16<<<5120, 256, 0, stream>>>(x, wq, wk, wv, wo, xh, w3h, woh);

    dim3 g1(1536 / 128, NTOK / 128);         // (12, 64)
    gemm_qkv_f16<<<g1, 256, 0, stream>>>(xh, w3h, qh, kh, vth);

    dim3 g2(Bsz * Hsz, Lsz / 64);            // (32 bh, 32 qb) — bh fastest
    attn_mfma<<<g2, 256, 0, stream>>>(qh, kh, vth, ctxh);

    dim3 g3(DIMsz / 64, NTOK / 64);          // (8, 128)
    gemm_out_f16<<<g3, 256, 0, stream>>>(ctxh, woh, out);
}